// Round 2
// baseline (7482.510 us; speedup 1.0000x reference)
//
#include <hip/hip_runtime.h>
#include <math.h>

// ============================================================================
// CrossAttention_Mirror: fp32 correctness baseline.
// Pipeline: conv1x1(+b) x2 -> cross flash-attn -> conv3x3+BN+ReLU -> cat(flow)
//           -> self flash-attn (C padded 258->320) -> conv3x3+BN+ReLU -> pred.
// ws layout: 5 slots of 4*320*4096 f32 (21MB) + stats + transformed conv wts.
// ============================================================================

#define NPIX 4096   // H*W = 64*64
#define NB   4

// ---------------- 1x1 conv as GEMM: Y[b,o,n] = sum_i W[o,i] X[b,i,n] (+bias)
// block 256 (16x16), tile 128x128, K-chunk 32, per-thread 8x8
__global__ __launch_bounds__(256) void gemm1x1_kernel(
    const float* __restrict__ X, const float* __restrict__ W,
    const float* __restrict__ Bias, float* __restrict__ Y,
    int I, int Ireal, int O, int Oreal, int N)
{
  const int b  = blockIdx.z;
  const int n0 = blockIdx.x * 128;
  const int o0 = blockIdx.y * 128;
  const int tid = threadIdx.x;
  const int tx = tid & 15, ty = tid >> 4;
  const float* Xb = X + (size_t)b * I * N;
  float*       Yb = Y + (size_t)b * O * N;

  __shared__ float As[32][130];  // [k][o] (+2 pad: 2-way is free)
  __shared__ float Bs[32][129];  // [k][n]

  float acc[8][8];
#pragma unroll
  for (int u = 0; u < 8; ++u)
#pragma unroll
    for (int v = 0; v < 8; ++v) acc[u][v] = 0.f;

  const int nchunk = (Ireal + 31) >> 5;
  for (int ch = 0; ch < nchunk; ++ch) {
    const int k0 = ch << 5;
    __syncthreads();
#pragma unroll
    for (int r = 0; r < 16; ++r) {           // 32x128 weights
      int e  = tid + r * 256;
      int kk = e & 31, oo = e >> 5;
      int i = k0 + kk, o = o0 + oo;
      As[kk][oo] = (i < Ireal && o < Oreal) ? W[(size_t)o * Ireal + i] : 0.f;
    }
#pragma unroll
    for (int r = 0; r < 16; ++r) {           // 32x128 activations
      int e  = tid + r * 256;
      int nn = e & 127, kk = e >> 7;
      int i = k0 + kk;
      Bs[kk][nn] = (i < I) ? Xb[(size_t)i * N + n0 + nn] : 0.f;
    }
    __syncthreads();
#pragma unroll 4
    for (int kk = 0; kk < 32; ++kk) {
      float a[8], bb[8];
#pragma unroll
      for (int u = 0; u < 8; ++u) a[u] = As[kk][ty + 16 * u];
#pragma unroll
      for (int v = 0; v < 8; ++v) bb[v] = Bs[kk][tx + 16 * v];
#pragma unroll
      for (int u = 0; u < 8; ++u)
#pragma unroll
        for (int v = 0; v < 8; ++v) acc[u][v] = fmaf(a[u], bb[v], acc[u][v]);
    }
  }
#pragma unroll
  for (int u = 0; u < 8; ++u) {
    int o = o0 + ty + 16 * u;
    if (o < O) {
      float bia = (Bias != nullptr && o < Oreal) ? Bias[o] : 0.f;
#pragma unroll
      for (int v = 0; v < 8; ++v)
        Yb[(size_t)o * N + n0 + tx + 16 * v] = acc[u][v] + bia;
    }
  }
}

// ---------------- flash attention (no 1/sqrt(d)), fp32, online softmax.
// Q,K,V,R,Out: [B][C][N].  Out = gamma * (V @ softmax(Q^T K)^T) + R.
// Out may alias Q (each block writes only its own n-columns, after last Q read).
// block 256 (16x16): n-tile 32 (rows ty+16u, u<2), m-tile 64 (cols tx+16v).
template<int C>
__global__ __launch_bounds__(256) void flash_kernel(
    const float* __restrict__ Q, const float* __restrict__ K,
    const float* __restrict__ V, const float* __restrict__ R,
    float* __restrict__ Out, const float* __restrict__ gamma_p, int N)
{
  constexpr int CW  = C / 16;   // acc channels per thread
  constexpr int NCH = C / 64;   // channel chunks
  const int b  = blockIdx.y;
  const int n0 = blockIdx.x * 32;
  const int tid = threadIdx.x;
  const int tx = tid & 15, ty = tid >> 4;
  const size_t base = (size_t)b * C * N;
  const float* Qb = Q + base;
  const float* Kb = K + base;
  const float* Vb = V + base;
  const float* Rb = R + base;
  float*       Ob = Out + base;

  __shared__ float Qs[64][33];  // [c-chunk][n]
  __shared__ float Ks[64][65];  // [c-chunk][m]
  __shared__ float Ps[32][65];  // [n][m]
  __shared__ float Vs[64][65];  // [c-chunk][m]

  float acc[2][CW];
#pragma unroll
  for (int u = 0; u < 2; ++u)
#pragma unroll
    for (int w = 0; w < CW; ++w) acc[u][w] = 0.f;
  float mrun[2], lrun[2];
#pragma unroll
  for (int u = 0; u < 2; ++u) { mrun[u] = -INFINITY; lrun[u] = 0.f; }

  for (int m0 = 0; m0 < N; m0 += 64) {
    // ----- S = Q^T K for this tile
    float s[2][4];
#pragma unroll
    for (int u = 0; u < 2; ++u)
#pragma unroll
      for (int v = 0; v < 4; ++v) s[u][v] = 0.f;
#pragma unroll
    for (int ch = 0; ch < NCH; ++ch) {
      const int c0 = ch * 64;
      __syncthreads();
      for (int e = tid; e < 2048; e += 256) {      // Q chunk [64c][32n]
        int cc = e >> 5, nn = e & 31;
        Qs[cc][nn] = Qb[(size_t)(c0 + cc) * N + n0 + nn];
      }
      for (int e = tid; e < 4096; e += 256) {      // K chunk [64c][64m]
        int cc = e >> 6, mm = e & 63;
        Ks[cc][mm] = Kb[(size_t)(c0 + cc) * N + m0 + mm];
      }
      __syncthreads();
#pragma unroll 4
      for (int kk = 0; kk < 64; ++kk) {
        float a[2], bb[4];
#pragma unroll
        for (int u = 0; u < 2; ++u) a[u] = Qs[kk][ty + 16 * u];
#pragma unroll
        for (int v = 0; v < 4; ++v) bb[v] = Ks[kk][tx + 16 * v];
#pragma unroll
        for (int u = 0; u < 2; ++u)
#pragma unroll
          for (int v = 0; v < 4; ++v) s[u][v] = fmaf(a[u], bb[v], s[u][v]);
      }
    }
    // ----- online softmax over m (rows = 16 consecutive lanes, shfl reduce)
#pragma unroll
    for (int u = 0; u < 2; ++u) {
      float pm = fmaxf(fmaxf(s[u][0], s[u][1]), fmaxf(s[u][2], s[u][3]));
#pragma unroll
      for (int off = 1; off < 16; off <<= 1) pm = fmaxf(pm, __shfl_xor(pm, off));
      float mnew = fmaxf(mrun[u], pm);
      float scal = __expf(mrun[u] - mnew);
      mrun[u] = mnew;
      float rs = 0.f;
#pragma unroll
      for (int v = 0; v < 4; ++v) { s[u][v] = __expf(s[u][v] - mnew); rs += s[u][v]; }
#pragma unroll
      for (int off = 1; off < 16; off <<= 1) rs += __shfl_xor(rs, off);
      lrun[u] = lrun[u] * scal + rs;
#pragma unroll
      for (int w = 0; w < CW; ++w) acc[u][w] *= scal;
    }
    __syncthreads();                 // prev-tile PV reads of Ps done
#pragma unroll
    for (int u = 0; u < 2; ++u)
#pragma unroll
      for (int v = 0; v < 4; ++v) Ps[ty + 16 * u][tx + 16 * v] = s[u][v];
    __syncthreads();
    // ----- O += P V^T  (per c-chunk)
#pragma unroll
    for (int ch = 0; ch < NCH; ++ch) {
      const int c0 = ch * 64;
      __syncthreads();
      for (int e = tid; e < 4096; e += 256) {
        int cc = e >> 6, mm = e & 63;
        Vs[cc][mm] = Vb[(size_t)(c0 + cc) * N + m0 + mm];
      }
      __syncthreads();
#pragma unroll 4
      for (int mm = 0; mm < 64; ++mm) {
        float pr[2], vv[4];
#pragma unroll
        for (int u = 0; u < 2; ++u) pr[u] = Ps[ty + 16 * u][mm];
#pragma unroll
        for (int w4 = 0; w4 < 4; ++w4) vv[w4] = Vs[tx + 16 * w4][mm];
#pragma unroll
        for (int u = 0; u < 2; ++u)
#pragma unroll
          for (int w4 = 0; w4 < 4; ++w4)
            acc[u][ch * 4 + w4] = fmaf(pr[u], vv[w4], acc[u][ch * 4 + w4]);
      }
    }
  }
  // ----- epilogue: gamma * O/l + residual
  const float g = *gamma_p;
#pragma unroll
  for (int u = 0; u < 2; ++u) {
    const float rinv = 1.f / lrun[u];
    const int n = n0 + ty + 16 * u;
#pragma unroll
    for (int w = 0; w < CW; ++w) {
      const int c = (w >> 2) * 64 + 16 * (w & 3) + tx;
      Ob[(size_t)c * N + n] = g * acc[u][w] * rinv + Rb[(size_t)c * N + n];
    }
  }
}

// ---------------- weight transform [O][I][3][3] -> [3][3][I][O] (coalesced A reads)
__global__ void wtrans_kernel(const float* __restrict__ Win, float* __restrict__ Wout,
                              int O, int I)
{
  size_t total = (size_t)O * I * 9;
  for (size_t e = (size_t)blockIdx.x * 256 + threadIdx.x; e < total;
       e += (size_t)gridDim.x * 256) {
    int o = (int)(e % O);
    size_t r = e / O;
    int i = (int)(r % I);
    int t = (int)(r / I);            // t = dy*3+dx
    Wout[e] = Win[((size_t)o * I + i) * 9 + t];
  }
}

// ---------------- conv3x3 SAME: Y[b,o,h,w] = sum_{i,dy,dx} W2[dy][dx][i][o] X[b,i,h+dy-1,w+dx-1]
// block 256 (16x16): o-tile 128 (rows ty+16u, u<8), one image row (w = tx+16v, v<4)
__global__ __launch_bounds__(256) void conv3x3_kernel(
    const float* __restrict__ X, const float* __restrict__ W2,
    float* __restrict__ Y, int Cin, int Ireal, int O, int N)
{
  const int b  = blockIdx.z;
  const int h  = blockIdx.x;
  const int o0 = blockIdx.y * 128;
  const int tid = threadIdx.x;
  const int tx = tid & 15, ty = tid >> 4;
  const float* Xb = X + (size_t)b * Cin * N;
  float*       Yb = Y + (size_t)b * O * N;

  __shared__ float As[3][32][130];   // [dx][k][o]
  __shared__ float Xs[32][64];       // [k][w]

  float acc[8][4];
#pragma unroll
  for (int u = 0; u < 8; ++u)
#pragma unroll
    for (int v = 0; v < 4; ++v) acc[u][v] = 0.f;

  const int nchunk = (Ireal + 31) >> 5;
  for (int ch = 0; ch < nchunk; ++ch) {
    const int c0 = ch << 5;
    for (int dy = 0; dy < 3; ++dy) {
      const int hs = h + dy - 1;
      const bool hv = (hs >= 0) && (hs < 64);
      __syncthreads();
      for (int e = tid; e < 2048; e += 256) {        // X row chunk
        int kk = e >> 6, w = e & 63;
        float val = 0.f;
        if (hv) val = Xb[(size_t)(c0 + kk) * N + hs * 64 + w];
        Xs[kk][w] = val;
      }
      for (int e = tid; e < 12288; e += 256) {       // 3 dx-planes of weights
        int oo = e & 127;
        int kd = e >> 7;
        int kk = kd & 31, dx = kd >> 5;
        int i = c0 + kk;
        As[dx][kk][oo] = (i < Ireal)
            ? W2[((size_t)(dy * 3 + dx) * Ireal + i) * O + o0 + oo] : 0.f;
      }
      __syncthreads();
#pragma unroll
      for (int dx = 0; dx < 3; ++dx) {
#pragma unroll 4
        for (int kk = 0; kk < 32; ++kk) {
          float a[8], bb[4];
#pragma unroll
          for (int u = 0; u < 8; ++u) a[u] = As[dx][kk][ty + 16 * u];
#pragma unroll
          for (int v = 0; v < 4; ++v) {
            int wi = tx + 16 * v + dx - 1;
            bb[v] = (wi >= 0 && wi < 64) ? Xs[kk][wi] : 0.f;
          }
#pragma unroll
          for (int u = 0; u < 8; ++u)
#pragma unroll
            for (int v = 0; v < 4; ++v) acc[u][v] = fmaf(a[u], bb[v], acc[u][v]);
        }
      }
    }
  }
#pragma unroll
  for (int u = 0; u < 8; ++u) {
    int o = o0 + ty + 16 * u;
#pragma unroll
    for (int v = 0; v < 4; ++v)
      Yb[(size_t)o * N + h * 64 + tx + 16 * v] = acc[u][v];
  }
}

// ---------------- BN stats (biased var over B,H,W), one block per channel
__global__ __launch_bounds__(256) void bn_stats_kernel(
    const float* __restrict__ X, float* __restrict__ Mean, float* __restrict__ Rstd,
    int Cstride, int N)
{
  const int c = blockIdx.x;
  float s = 0.f, sq = 0.f;
  for (int b = 0; b < NB; ++b) {
    const float* p = X + ((size_t)b * Cstride + c) * N;
    for (int n = threadIdx.x; n < N; n += 256) {
      float v = p[n];
      s += v; sq += v * v;
    }
  }
  __shared__ float rs[256], rq[256];
  rs[threadIdx.x] = s; rq[threadIdx.x] = sq;
  __syncthreads();
  for (int st = 128; st > 0; st >>= 1) {
    if (threadIdx.x < st) { rs[threadIdx.x] += rs[threadIdx.x + st];
                            rq[threadIdx.x] += rq[threadIdx.x + st]; }
    __syncthreads();
  }
  if (threadIdx.x == 0) {
    const float inv = 1.f / (float)(NB * N);
    float mean = rs[0] * inv;
    float var  = rq[0] * inv - mean * mean;
    Mean[c] = mean;
    Rstd[c] = 1.f / sqrtf(var + 1e-5f);
  }
}

// ---------------- BN apply + ReLU (+ optional flow concat + zero-pad channels)
__global__ __launch_bounds__(256) void bn_apply_kernel(
    const float* __restrict__ X, const float* __restrict__ Flow,
    const float* __restrict__ Mean, const float* __restrict__ Rstd,
    const float* __restrict__ Gm, const float* __restrict__ Bt,
    float* __restrict__ Y, int Cy, int N, int hasflow)
{
  size_t idx = (size_t)blockIdx.x * 256 + threadIdx.x;
  size_t total = (size_t)NB * Cy * N;
  if (idx >= total) return;
  int n = (int)(idx & (N - 1));
  size_t r = idx >> 12;               // N == 4096
  int c = (int)(r % Cy);
  int b = (int)(r / Cy);
  float val;
  if (c < 256) {
    float x = X[((size_t)b * 256 + c) * N + n];
    float xn = (x - Mean[c]) * Rstd[c];
    val = fmaxf(xn * Gm[c] + Bt[c], 0.f);
  } else if (hasflow && c < 258) {
    val = Flow[((size_t)b * 2 + (c - 256)) * N + n];
  } else {
    val = 0.f;
  }
  Y[idx] = val;
}

// ---------------- pred: out[b,n] = sum_c W[c] X[b,c,n] + bias
__global__ __launch_bounds__(256) void pred_kernel(
    const float* __restrict__ X, const float* __restrict__ W,
    const float* __restrict__ Bias, float* __restrict__ Out, int C, int N)
{
  int b = blockIdx.y;
  int n = blockIdx.x * 256 + threadIdx.x;
  const float* Xb = X + (size_t)b * C * N;
  float acc = 0.f;
  for (int c = 0; c < 256; ++c) acc = fmaf(W[c], Xb[(size_t)c * N + n], acc);
  Out[(size_t)b * N + n] = acc + Bias[0];
}

// ============================================================================
extern "C" void kernel_launch(void* const* d_in, const int* in_sizes, int n_in,
                              void* d_out, int out_size, void* d_ws, size_t ws_size,
                              hipStream_t stream)
{
  (void)in_sizes; (void)n_in; (void)out_size; (void)ws_size;
  const float* x      = (const float*)d_in[0];
  const float* y      = (const float*)d_in[1];
  const float* flow   = (const float*)d_in[2];
  const float* w1x1   = (const float*)d_in[3];
  const float* b1x1   = (const float*)d_in[4];
  const float* ca_wq  = (const float*)d_in[5];
  const float* ca_wk  = (const float*)d_in[6];
  const float* ca_wv  = (const float*)d_in[7];
  const float* ca_g   = (const float*)d_in[8];
  const float* cbr1_w = (const float*)d_in[9];
  const float* bn1_g  = (const float*)d_in[10];
  const float* bn1_b  = (const float*)d_in[11];
  const float* sa_wq  = (const float*)d_in[12];
  const float* sa_wk  = (const float*)d_in[13];
  const float* sa_wv  = (const float*)d_in[14];
  const float* sa_g   = (const float*)d_in[15];
  const float* cbr2_w = (const float*)d_in[16];
  const float* bn2_g  = (const float*)d_in[17];
  const float* bn2_b  = (const float*)d_in[18];
  const float* pred_w = (const float*)d_in[19];
  const float* pred_b = (const float*)d_in[20];
  float* out = (float*)d_out;

  const int N = NPIX;
  const size_t SLOT = (size_t)NB * 320 * NPIX;   // 5,242,880 floats
  float* ws = (float*)d_ws;
  float* A  = ws + 0 * SLOT;   // xb -> conv1 raw -> conv2 raw
  float* Bf = ws + 1 * SLOT;   // yb -> flash1 out(t) ... cat
  float* Cc = ws + 2 * SLOT;   // q -> t (flash1 out aliases q) -> q2 -> t2
  float* D  = ws + 3 * SLOT;   // k -> k2 -> bn2 out
  float* E  = ws + 4 * SLOT;   // v -> v2
  float* mean1 = ws + 5 * SLOT;
  float* rstd1 = mean1 + 256;
  float* w2a   = rstd1 + 256;              // conv1 wts [3][3][256][256]
  float* w2b   = w2a + (size_t)9 * 256 * 256;  // conv2 wts [3][3][258][256]

  dim3 blk(256);

  // conv weight transforms (independent of activations)
  wtrans_kernel<<<dim3(512), blk, 0, stream>>>(cbr1_w, w2a, 256, 256);
  wtrans_kernel<<<dim3(512), blk, 0, stream>>>(cbr2_w, w2b, 256, 258);

  // xb = W1 x + b1 ; yb = W1 y + b1
  gemm1x1_kernel<<<dim3(32, 2, 4), blk, 0, stream>>>(x, w1x1, b1x1, A, 512, 512, 256, 256, N);
  gemm1x1_kernel<<<dim3(32, 2, 4), blk, 0, stream>>>(y, w1x1, b1x1, Bf, 512, 512, 256, 256, N);

  // q,k,v (no bias)
  gemm1x1_kernel<<<dim3(32, 2, 4), blk, 0, stream>>>(A,  ca_wq, nullptr, Cc, 256, 256, 256, 256, N);
  gemm1x1_kernel<<<dim3(32, 2, 4), blk, 0, stream>>>(Bf, ca_wk, nullptr, D,  256, 256, 256, 256, N);
  gemm1x1_kernel<<<dim3(32, 2, 4), blk, 0, stream>>>(Bf, ca_wv, nullptr, E,  256, 256, 256, 256, N);

  // cross-attn: t = gamma * attn(q,k,v) + xb   (out aliases q)
  flash_kernel<256><<<dim3(128, 4), blk, 0, stream>>>(Cc, D, E, A, Cc, ca_g, N);

  // conv3x3 + BN + ReLU -> cat with flow into 320-ch (zeros beyond 258)
  conv3x3_kernel<<<dim3(64, 2, 4), blk, 0, stream>>>(Cc, w2a, A, 256, 256, 256, N);
  bn_stats_kernel<<<dim3(256), blk, 0, stream>>>(A, mean1, rstd1, 256, N);
  bn_apply_kernel<<<dim3(20480), blk, 0, stream>>>(A, flow, mean1, rstd1, bn1_g, bn1_b,
                                                   Bf, 320, N, 1);

  // self-attn qkv (padded O=320, real 258)
  gemm1x1_kernel<<<dim3(32, 3, 4), blk, 0, stream>>>(Bf, sa_wq, nullptr, Cc, 320, 258, 320, 258, N);
  gemm1x1_kernel<<<dim3(32, 3, 4), blk, 0, stream>>>(Bf, sa_wk, nullptr, D,  320, 258, 320, 258, N);
  gemm1x1_kernel<<<dim3(32, 3, 4), blk, 0, stream>>>(Bf, sa_wv, nullptr, E,  320, 258, 320, 258, N);

  // self-attn: t2 = gamma * attn + cat   (out aliases q2; pad channels stay 0)
  flash_kernel<320><<<dim3(128, 4), blk, 0, stream>>>(Cc, D, E, Bf, Cc, sa_g, N);

  // conv3x3 #2 + BN + ReLU
  conv3x3_kernel<<<dim3(64, 2, 4), blk, 0, stream>>>(Cc, w2b, A, 320, 258, 256, N);
  bn_stats_kernel<<<dim3(256), blk, 0, stream>>>(A, mean1, rstd1, 256, N);
  bn_apply_kernel<<<dim3(16384), blk, 0, stream>>>(A, nullptr, mean1, rstd1, bn2_g, bn2_b,
                                                   D, 256, N, 0);

  // pred 1x1 (O=1)
  pred_kernel<<<dim3(16, 4), blk, 0, stream>>>(D, pred_w, pred_b, out, 256, N);
}

// Round 3
// 3345.288 us; speedup vs baseline: 2.2367x; 2.2367x over previous
//
#include <hip/hip_runtime.h>
#include <hip/hip_bf16.h>
#include <math.h>

// ============================================================================
// CrossAttention_Mirror round 2: MFMA bf16 flash attention (split-bf16 QK^T).
// Pipeline: conv1x1(+b) x2 -> [qkv gemm -> bf16 hi/lo] -> MFMA flash -> conv3x3
//           +BN+ReLU -> cat(flow, pad 288) -> qkv -> MFMA flash -> conv3x3+BN
//           +ReLU -> pred.
// ============================================================================

#define NPIX 4096   // H*W
#define NB   4

typedef __attribute__((ext_vector_type(8))) short short8v;
typedef __attribute__((ext_vector_type(4))) float float4v;

// ---------------- 1x1 conv as GEMM: Y[b,o,n] = sum_i W[o,i] X[b,i,n]
// OMODE 0: fp32 out (+bias). OMODE 1: bf16 hi/lo pair, layout [N][O] (for q,k).
// OMODE 2: bf16 hi only, layout [O][N] (for v).
template<int OMODE>
__global__ __launch_bounds__(256) void gemm1x1_t(
    const float* __restrict__ X, const float* __restrict__ W,
    const float* __restrict__ Bias, float* __restrict__ Yf,
    __hip_bfloat16* __restrict__ Yh, __hip_bfloat16* __restrict__ Yl,
    int I, int Ireal, int O, int Oreal, int N)
{
  const int b  = blockIdx.z;
  const int n0 = blockIdx.x * 128;
  const int o0 = blockIdx.y * 128;
  const int tid = threadIdx.x;
  const int tx = tid & 15, ty = tid >> 4;
  const float* Xb = X + (size_t)b * I * N;

  __shared__ float As[32][130];
  __shared__ float Bs[32][129];

  float acc[8][8];
#pragma unroll
  for (int u = 0; u < 8; ++u)
#pragma unroll
    for (int v = 0; v < 8; ++v) acc[u][v] = 0.f;

  const int nchunk = (Ireal + 31) >> 5;
  for (int ch = 0; ch < nchunk; ++ch) {
    const int k0 = ch << 5;
    __syncthreads();
#pragma unroll
    for (int r = 0; r < 16; ++r) {
      int e  = tid + r * 256;
      int kk = e & 31, oo = e >> 5;
      int i = k0 + kk, o = o0 + oo;
      As[kk][oo] = (i < Ireal && o < Oreal) ? W[(size_t)o * Ireal + i] : 0.f;
    }
#pragma unroll
    for (int r = 0; r < 16; ++r) {
      int e  = tid + r * 256;
      int nn = e & 127, kk = e >> 7;
      int i = k0 + kk;
      Bs[kk][nn] = (i < I) ? Xb[(size_t)i * N + n0 + nn] : 0.f;
    }
    __syncthreads();
#pragma unroll 4
    for (int kk = 0; kk < 32; ++kk) {
      float a[8], bb[8];
#pragma unroll
      for (int u = 0; u < 8; ++u) a[u] = As[kk][ty + 16 * u];
#pragma unroll
      for (int v = 0; v < 8; ++v) bb[v] = Bs[kk][tx + 16 * v];
#pragma unroll
      for (int u = 0; u < 8; ++u)
#pragma unroll
        for (int v = 0; v < 8; ++v) acc[u][v] = fmaf(a[u], bb[v], acc[u][v]);
    }
  }
#pragma unroll
  for (int u = 0; u < 8; ++u) {
    int o = o0 + ty + 16 * u;
    if (o < O) {
      if (OMODE == 0) {
        float bia = (Bias != nullptr && o < Oreal) ? Bias[o] : 0.f;
        float* Yb = Yf + (size_t)b * O * N;
#pragma unroll
        for (int v = 0; v < 8; ++v)
          Yb[(size_t)o * N + n0 + tx + 16 * v] = acc[u][v] + bia;
      } else if (OMODE == 1) {
        __hip_bfloat16* Hb = Yh + (size_t)b * N * O;
        __hip_bfloat16* Lb = Yl + (size_t)b * N * O;
#pragma unroll
        for (int v = 0; v < 8; ++v) {
          float xv = acc[u][v];
          __hip_bfloat16 h = __float2bfloat16(xv);
          float lo = xv - __bfloat162float(h);
          size_t idx = (size_t)(n0 + tx + 16 * v) * O + o;
          Hb[idx] = h;
          Lb[idx] = __float2bfloat16(lo);
        }
      } else {
        __hip_bfloat16* Hb = Yh + (size_t)b * O * N;
#pragma unroll
        for (int v = 0; v < 8; ++v)
          Hb[(size_t)o * N + n0 + tx + 16 * v] = __float2bfloat16(acc[u][v]);
      }
    }
  }
}

// ---------------- MFMA flash attention.
// Qh/Ql/Kh/Kl: [B][N][C] bf16 (c-contiguous). Vh: [B][C][N] bf16.
// R, Out: [B][C][N] fp32.  Out = gamma * softmax(Q^T K)-weighted V + R.
// Block: 256 thr (4 waves), 64 q-rows/block, m-tile 64, full-C K/V staged.
template<int C, int SWK>
__global__ __launch_bounds__(256, 1) void flash_mfma_kernel(
    const __hip_bfloat16* __restrict__ Qh, const __hip_bfloat16* __restrict__ Ql,
    const __hip_bfloat16* __restrict__ Kh, const __hip_bfloat16* __restrict__ Kl,
    const __hip_bfloat16* __restrict__ Vh, const float* __restrict__ R,
    float* __restrict__ Out, const float* __restrict__ gamma_p)
{
  constexpr int N    = NPIX;
  constexpr int NC32 = C / 32;   // k-steps over channels
  constexpr int NCF  = C / 16;   // output c-fragments
  const int b  = blockIdx.y;
  const int n0 = blockIdx.x * 64;
  const int tid  = threadIdx.x;
  const int w    = tid >> 6;
  const int lane = tid & 63;
  const int lg   = lane >> 4;    // 0..3
  const int lr   = lane & 15;    // 0..15

  __shared__ __align__(16) __hip_bfloat16 KtH[64 * C];   // [m][c] swizzled
  __shared__ __align__(16) __hip_bfloat16 KtL[64 * C];
  __shared__ __align__(16) __hip_bfloat16 Vs[C * 64];    // [c][m] swizzled
  __shared__ __align__(16) __hip_bfloat16 Ps[64 * 72];   // [n][m] pitch 72

  // ----- Q fragments to registers (hi+lo), row n = n0+16w+lr, k = 8*lg+i
  short8v qhf[NC32], qlf[NC32];
  {
    const size_t qoff = ((size_t)b * N + n0 + 16 * w + lr) * C + 8 * lg;
    const short8v* ph = (const short8v*)(Qh + qoff);
    const short8v* pl = (const short8v*)(Ql + qoff);
#pragma unroll
    for (int kc = 0; kc < NC32; ++kc) { qhf[kc] = ph[kc * 4]; qlf[kc] = pl[kc * 4]; }
  }

  float4v oacc[NCF];
#pragma unroll
  for (int f = 0; f < NCF; ++f) oacc[f] = (float4v){0.f, 0.f, 0.f, 0.f};
  float mrun[4], lrun[4];
#pragma unroll
  for (int r = 0; r < 4; ++r) { mrun[r] = -INFINITY; lrun[r] = 0.f; }

  constexpr int segK = (64 * C) / 8;
  constexpr int segV = (C * 64) / 8;

  for (int m0 = 0; m0 < N; m0 += 64) {
    __syncthreads();                         // prev-tile frag reads done
    // ----- stage K (hi+lo), transposed-in-global layout already [m][c]
    for (int s = tid; s < segK; s += 256) {
      int row = s / (C / 8);
      int c8  = (s % (C / 8)) * 8;
      size_t g = ((size_t)b * N + m0 + row) * C + c8;
      int l = row * C + (c8 ^ (8 * (row & SWK)));
      *(short8v*)(KtH + l) = *(const short8v*)(Kh + g);
      *(short8v*)(KtL + l) = *(const short8v*)(Kl + g);
    }
    // ----- stage V [c][m]
    for (int s = tid; s < segV; s += 256) {
      int c  = s >> 3;
      int m8 = (s & 7) * 8;
      size_t g = ((size_t)b * C + c) * N + m0 + m8;
      int l = c * 64 + (m8 ^ (8 * (c & 7)));
      *(short8v*)(Vs + l) = *(const short8v*)(Vh + g);
    }
    __syncthreads();

    // ----- S = Q^T K (split-bf16: qh*kh + ql*kh + qh*kl)
    float4v sacc[4];
#pragma unroll
    for (int mf = 0; mf < 4; ++mf) sacc[mf] = (float4v){0.f, 0.f, 0.f, 0.f};
#pragma unroll
    for (int ks = 0; ks < NC32; ++ks) {
#pragma unroll
      for (int mf = 0; mf < 4; ++mf) {
        int m  = 16 * mf + lr;
        int c8 = 32 * ks + 8 * lg;
        int l  = m * C + (c8 ^ (8 * (m & SWK)));
        short8v kh8 = *(short8v*)(KtH + l);
        short8v kl8 = *(short8v*)(KtL + l);
        sacc[mf] = __builtin_amdgcn_mfma_f32_16x16x32_bf16(qhf[ks], kh8, sacc[mf], 0, 0, 0);
        sacc[mf] = __builtin_amdgcn_mfma_f32_16x16x32_bf16(qlf[ks], kh8, sacc[mf], 0, 0, 0);
        sacc[mf] = __builtin_amdgcn_mfma_f32_16x16x32_bf16(qhf[ks], kl8, sacc[mf], 0, 0, 0);
      }
    }

    // ----- online softmax (rows n = 16w + 4lg + r; 16-lane shfl reduce)
    float scal[4];
#pragma unroll
    for (int r = 0; r < 4; ++r) {
      float pm = fmaxf(fmaxf(sacc[0][r], sacc[1][r]), fmaxf(sacc[2][r], sacc[3][r]));
#pragma unroll
      for (int off = 1; off < 16; off <<= 1) pm = fmaxf(pm, __shfl_xor(pm, off));
      float mnew = fmaxf(mrun[r], pm);
      float sc = __expf(mrun[r] - mnew);
      mrun[r] = mnew;
      float rs = 0.f;
      float p[4];
#pragma unroll
      for (int f = 0; f < 4; ++f) { p[f] = __expf(sacc[f][r] - mnew); rs += p[f]; }
#pragma unroll
      for (int f = 0; f < 4; ++f)
        Ps[(16 * w + 4 * lg + r) * 72 + 16 * f + lr] = __float2bfloat16(p[f]);
#pragma unroll
      for (int off = 1; off < 16; off <<= 1) rs += __shfl_xor(rs, off);
      lrun[r] = lrun[r] * sc + rs;
      scal[r] = sc;
    }
#pragma unroll
    for (int f = 0; f < NCF; ++f)
#pragma unroll
      for (int r = 0; r < 4; ++r) oacc[f][r] *= scal[r];

    // P writes are wave-private (rows 16w..16w+15); drain LDS before reads.
    asm volatile("s_waitcnt lgkmcnt(0)" ::: "memory");

    // ----- O += P V^T
    short8v pa0 = *(short8v*)(Ps + (16 * w + lr) * 72 + 8 * lg);
    short8v pa1 = *(short8v*)(Ps + (16 * w + lr) * 72 + 32 + 8 * lg);
#pragma unroll
    for (int cf = 0; cf < NCF; ++cf) {
      int c = 16 * cf + lr;
      int base = c * 64;
      int sw = 8 * (c & 7);
      short8v v0 = *(short8v*)(Vs + base + ((8 * lg) ^ sw));
      short8v v1 = *(short8v*)(Vs + base + ((32 + 8 * lg) ^ sw));
      oacc[cf] = __builtin_amdgcn_mfma_f32_16x16x32_bf16(pa0, v0, oacc[cf], 0, 0, 0);
      oacc[cf] = __builtin_amdgcn_mfma_f32_16x16x32_bf16(pa1, v1, oacc[cf], 0, 0, 0);
    }
  }

  // ----- epilogue: gamma * O/l + residual
  const float gm = *gamma_p;
#pragma unroll
  for (int r = 0; r < 4; ++r) {
    float inv = 1.f / lrun[r];
    int n = n0 + 16 * w + 4 * lg + r;
#pragma unroll
    for (int cf = 0; cf < NCF; ++cf) {
      int c = 16 * cf + lr;
      size_t off = ((size_t)b * C + c) * N + n;
      Out[off] = gm * oacc[cf][r] * inv + R[off];
    }
  }
}

// ---------------- weight transform [O][I][3][3] -> [3][3][I][O]
__global__ void wtrans_kernel(const float* __restrict__ Win, float* __restrict__ Wout,
                              int O, int I)
{
  size_t total = (size_t)O * I * 9;
  for (size_t e = (size_t)blockIdx.x * 256 + threadIdx.x; e < total;
       e += (size_t)gridDim.x * 256) {
    int o = (int)(e % O);
    size_t r = e / O;
    int i = (int)(r % I);
    int t = (int)(r / I);
    Wout[e] = Win[((size_t)o * I + i) * 9 + t];
  }
}

// ---------------- conv3x3 SAME (fp32)
__global__ __launch_bounds__(256) void conv3x3_kernel(
    const float* __restrict__ X, const float* __restrict__ W2,
    float* __restrict__ Y, int Cin, int Ireal, int O, int N)
{
  const int b  = blockIdx.z;
  const int h  = blockIdx.x;
  const int o0 = blockIdx.y * 128;
  const int tid = threadIdx.x;
  const int tx = tid & 15, ty = tid >> 4;
  const float* Xb = X + (size_t)b * Cin * N;
  float*       Yb = Y + (size_t)b * O * N;

  __shared__ float As[3][32][130];
  __shared__ float Xs[32][64];

  float acc[8][4];
#pragma unroll
  for (int u = 0; u < 8; ++u)
#pragma unroll
    for (int v = 0; v < 4; ++v) acc[u][v] = 0.f;

  const int nchunk = (Ireal + 31) >> 5;
  for (int ch = 0; ch < nchunk; ++ch) {
    const int c0 = ch << 5;
    for (int dy = 0; dy < 3; ++dy) {
      const int hs = h + dy - 1;
      const bool hv = (hs >= 0) && (hs < 64);
      __syncthreads();
      for (int e = tid; e < 2048; e += 256) {
        int kk = e >> 6, ww = e & 63;
        float val = 0.f;
        if (hv) val = Xb[(size_t)(c0 + kk) * N + hs * 64 + ww];
        Xs[kk][ww] = val;
      }
      for (int e = tid; e < 12288; e += 256) {
        int oo = e & 127;
        int kd = e >> 7;
        int kk = kd & 31, dx = kd >> 5;
        int i = c0 + kk;
        As[dx][kk][oo] = (i < Ireal)
            ? W2[((size_t)(dy * 3 + dx) * Ireal + i) * O + o0 + oo] : 0.f;
      }
      __syncthreads();
#pragma unroll
      for (int dx = 0; dx < 3; ++dx) {
#pragma unroll 4
        for (int kk = 0; kk < 32; ++kk) {
          float a[8], bb[4];
#pragma unroll
          for (int u = 0; u < 8; ++u) a[u] = As[dx][kk][ty + 16 * u];
#pragma unroll
          for (int v = 0; v < 4; ++v) {
            int wi = tx + 16 * v + dx - 1;
            bb[v] = (wi >= 0 && wi < 64) ? Xs[kk][wi] : 0.f;
          }
#pragma unroll
          for (int u = 0; u < 8; ++u)
#pragma unroll
            for (int v = 0; v < 4; ++v) acc[u][v] = fmaf(a[u], bb[v], acc[u][v]);
        }
      }
    }
  }
#pragma unroll
  for (int u = 0; u < 8; ++u) {
    int o = o0 + ty + 16 * u;
#pragma unroll
    for (int v = 0; v < 4; ++v)
      Yb[(size_t)o * N + h * 64 + tx + 16 * v] = acc[u][v];
  }
}

// ---------------- BN stats
__global__ __launch_bounds__(256) void bn_stats_kernel(
    const float* __restrict__ X, float* __restrict__ Mean, float* __restrict__ Rstd,
    int Cstride, int N)
{
  const int c = blockIdx.x;
  float s = 0.f, sq = 0.f;
  for (int b = 0; b < NB; ++b) {
    const float* p = X + ((size_t)b * Cstride + c) * N;
    for (int n = threadIdx.x; n < N; n += 256) {
      float v = p[n];
      s += v; sq += v * v;
    }
  }
  __shared__ float rs[256], rq[256];
  rs[threadIdx.x] = s; rq[threadIdx.x] = sq;
  __syncthreads();
  for (int st = 128; st > 0; st >>= 1) {
    if (threadIdx.x < st) { rs[threadIdx.x] += rs[threadIdx.x + st];
                            rq[threadIdx.x] += rq[threadIdx.x + st]; }
    __syncthreads();
  }
  if (threadIdx.x == 0) {
    const float inv = 1.f / (float)(NB * N);
    float mean = rs[0] * inv;
    float var  = rq[0] * inv - mean * mean;
    Mean[c] = mean;
    Rstd[c] = 1.f / sqrtf(var + 1e-5f);
  }
}

// ---------------- BN apply + ReLU (+ flow concat + zero-pad)
__global__ __launch_bounds__(256) void bn_apply_kernel(
    const float* __restrict__ X, const float* __restrict__ Flow,
    const float* __restrict__ Mean, const float* __restrict__ Rstd,
    const float* __restrict__ Gm, const float* __restrict__ Bt,
    float* __restrict__ Y, int Cy, int N, int hasflow)
{
  size_t idx = (size_t)blockIdx.x * 256 + threadIdx.x;
  size_t total = (size_t)NB * Cy * N;
  if (idx >= total) return;
  int n = (int)(idx & (N - 1));
  size_t r = idx >> 12;
  int c = (int)(r % Cy);
  int b = (int)(r / Cy);
  float val;
  if (c < 256) {
    float x = X[((size_t)b * 256 + c) * N + n];
    float xn = (x - Mean[c]) * Rstd[c];
    val = fmaxf(xn * Gm[c] + Bt[c], 0.f);
  } else if (hasflow && c < 258) {
    val = Flow[((size_t)b * 2 + (c - 256)) * N + n];
  } else {
    val = 0.f;
  }
  Y[idx] = val;
}

// ---------------- pred 1x1 (O=1)
__global__ __launch_bounds__(256) void pred_kernel(
    const float* __restrict__ X, const float* __restrict__ W,
    const float* __restrict__ Bias, float* __restrict__ Out, int C, int N)
{
  int b = blockIdx.y;
  int n = blockIdx.x * 256 + threadIdx.x;
  const float* Xb = X + (size_t)b * C * N;
  float acc = 0.f;
  for (int c = 0; c < 256; ++c) acc = fmaf(W[c], Xb[(size_t)c * N + n], acc);
  Out[(size_t)b * N + n] = acc + Bias[0];
}

// ============================================================================
extern "C" void kernel_launch(void* const* d_in, const int* in_sizes, int n_in,
                              void* d_out, int out_size, void* d_ws, size_t ws_size,
                              hipStream_t stream)
{
  (void)in_sizes; (void)n_in; (void)out_size; (void)ws_size;
  const float* x      = (const float*)d_in[0];
  const float* y      = (const float*)d_in[1];
  const float* flow   = (const float*)d_in[2];
  const float* w1x1   = (const float*)d_in[3];
  const float* b1x1   = (const float*)d_in[4];
  const float* ca_wq  = (const float*)d_in[5];
  const float* ca_wk  = (const float*)d_in[6];
  const float* ca_wv  = (const float*)d_in[7];
  const float* ca_g   = (const float*)d_in[8];
  const float* cbr1_w = (const float*)d_in[9];
  const float* bn1_g  = (const float*)d_in[10];
  const float* bn1_b  = (const float*)d_in[11];
  const float* sa_wq  = (const float*)d_in[12];
  const float* sa_wk  = (const float*)d_in[13];
  const float* sa_wv  = (const float*)d_in[14];
  const float* sa_g   = (const float*)d_in[15];
  const float* cbr2_w = (const float*)d_in[16];
  const float* bn2_g  = (const float*)d_in[17];
  const float* bn2_b  = (const float*)d_in[18];
  const float* pred_w = (const float*)d_in[19];
  const float* pred_b = (const float*)d_in[20];
  float* out = (float*)d_out;

  const int N = NPIX;
  const size_t SLOT = (size_t)NB * 288 * NPIX;        // 4,718,592 floats
  float* ws = (float*)d_ws;
  float* A  = ws + 0 * SLOT;   // xb -> conv raw (x2)
  float* Bf = ws + 1 * SLOT;   // yb -> cat(288) -> bn2 out(256)
  float* Cc = ws + 2 * SLOT;   // flash outs t(256)/t2(288)
  __hip_bfloat16* qh = (__hip_bfloat16*)(ws + 3 * SLOT);
  __hip_bfloat16* ql = qh + SLOT;        // each SLOT bf16 elems (half the bytes)
  __hip_bfloat16* kh = ql + SLOT;
  __hip_bfloat16* kl = kh + SLOT;
  __hip_bfloat16* vh = kl + SLOT;
  float* w2a   = (float*)(vh + SLOT);                 // [3][3][256][256]
  float* w2b   = w2a + (size_t)9 * 256 * 256;         // [3][3][258][256]
  float* mean1 = w2b + (size_t)9 * 258 * 256;
  float* rstd1 = mean1 + 256;

  dim3 blk(256);

  wtrans_kernel<<<dim3(512), blk, 0, stream>>>(cbr1_w, w2a, 256, 256);
  wtrans_kernel<<<dim3(512), blk, 0, stream>>>(cbr2_w, w2b, 256, 258);

  // xb, yb (fp32)
  gemm1x1_t<0><<<dim3(32, 2, 4), blk, 0, stream>>>(x, w1x1, b1x1, A, nullptr, nullptr,
                                                   512, 512, 256, 256, N);
  gemm1x1_t<0><<<dim3(32, 2, 4), blk, 0, stream>>>(y, w1x1, b1x1, Bf, nullptr, nullptr,
                                                   512, 512, 256, 256, N);

  // cross qkv -> bf16
  gemm1x1_t<1><<<dim3(32, 2, 4), blk, 0, stream>>>(A,  ca_wq, nullptr, nullptr, qh, ql,
                                                   256, 256, 256, 256, N);
  gemm1x1_t<1><<<dim3(32, 2, 4), blk, 0, stream>>>(Bf, ca_wk, nullptr, nullptr, kh, kl,
                                                   256, 256, 256, 256, N);
  gemm1x1_t<2><<<dim3(32, 2, 4), blk, 0, stream>>>(Bf, ca_wv, nullptr, nullptr, vh, nullptr,
                                                   256, 256, 256, 256, N);

  // cross flash: t = gamma*attn + xb -> Cc (pitch 256)
  flash_mfma_kernel<256, 7><<<dim3(64, 4), blk, 0, stream>>>(qh, ql, kh, kl, vh, A, Cc, ca_g);

  // conv3x3 #1 + BN + ReLU -> cat(288: 256 bn | 2 flow | 30 zero) in Bf
  conv3x3_kernel<<<dim3(64, 2, 4), blk, 0, stream>>>(Cc, w2a, A, 256, 256, 256, N);
  bn_stats_kernel<<<dim3(256), blk, 0, stream>>>(A, mean1, rstd1, 256, N);
  bn_apply_kernel<<<dim3(18432), blk, 0, stream>>>(A, flow, mean1, rstd1, bn1_g, bn1_b,
                                                   Bf, 288, N, 1);

  // self qkv (C_pad=288, real 258)
  gemm1x1_t<1><<<dim3(32, 3, 4), blk, 0, stream>>>(Bf, sa_wq, nullptr, nullptr, qh, ql,
                                                   288, 258, 288, 258, N);
  gemm1x1_t<1><<<dim3(32, 3, 4), blk, 0, stream>>>(Bf, sa_wk, nullptr, nullptr, kh, kl,
                                                   288, 258, 288, 258, N);
  gemm1x1_t<2><<<dim3(32, 3, 4), blk, 0, stream>>>(Bf, sa_wv, nullptr, nullptr, vh, nullptr,
                                                   288, 258, 288, 258, N);

  // self flash: t2 = gamma*attn + cat -> Cc (pitch 288)
  flash_mfma_kernel<288, 3><<<dim3(64, 4), blk, 0, stream>>>(qh, ql, kh, kl, vh, Bf, Cc, sa_g);

  // conv3x3 #2 + BN + ReLU
  conv3x3_kernel<<<dim3(64, 2, 4), blk, 0, stream>>>(Cc, w2b, A, 288, 258, 256, N);
  bn_stats_kernel<<<dim3(256), blk, 0, stream>>>(A, mean1, rstd1, 256, N);
  bn_apply_kernel<<<dim3(16384), blk, 0, stream>>>(A, nullptr, mean1, rstd1, bn2_g, bn2_b,
                                                   Bf, 256, N, 0);

  pred_kernel<<<dim3(16, 4), blk, 0, stream>>>(Bf, pred_w, pred_b, out, 256, N);
}

// Round 4
// 625.435 us; speedup vs baseline: 11.9637x; 5.3487x over previous
//
#include <hip/hip_runtime.h>
#include <hip/hip_bf16.h>
#include <math.h>

// ============================================================================
// Round 3: full bf16-MFMA pipeline, channel-last activations.
// transpose(x,y) -> gemm(xb,yb) -> gemm(q,k,v) -> flash(split2)+merge ->
// conv3x3 MFMA + BN + cat -> gemm(q2,k2,v2) -> flash+merge -> conv3x3 + BN ->
// pred.
// ============================================================================

#define NPIX 4096
#define NB   4

typedef __attribute__((ext_vector_type(8))) short short8v;
typedef __attribute__((ext_vector_type(4))) float float4v;

__device__ __forceinline__ short f2bs(float f) {
  __hip_bfloat16 h = __float2bfloat16(f);
  short r; __builtin_memcpy(&r, &h, 2); return r;
}

// ---------------- transpose: x [B][512][N] f32 -> xT [B][N][512] bf16
__global__ __launch_bounds__(256) void transp_kernel(
    const float* __restrict__ X, __hip_bfloat16* __restrict__ XT)
{
  const int i0 = blockIdx.x * 64, n0 = blockIdx.y * 64, b = blockIdx.z;
  const int tid = threadIdx.x;
  __shared__ float Ls[64][68];
#pragma unroll
  for (int it = 0; it < 4; ++it) {
    int ir = it * 16 + (tid >> 4);
    int nc = (tid & 15) * 4;
    float4 v = *(const float4*)(X + ((size_t)b * 512 + i0 + ir) * NPIX + n0 + nc);
    *(float4*)(&Ls[ir][nc]) = v;
  }
  __syncthreads();
#pragma unroll
  for (int ot = 0; ot < 2; ++ot) {
    int n = ot * 32 + (tid >> 3);
    int ig = tid & 7;
    short8v o;
#pragma unroll
    for (int j = 0; j < 8; ++j) o[j] = f2bs(Ls[8 * ig + j][n]);
    *(short8v*)(XT + ((size_t)b * NPIX + n0 + n) * 512 + i0 + 8 * ig) = o;
  }
}

// ---------------- weight prep: f32 [Or][Ir] -> bf16 [Op][Ip] zero-padded
__global__ void wprep_kernel(const float* __restrict__ Win,
                             __hip_bfloat16* __restrict__ Wout,
                             int Or, int Ir, int Op, int Ip)
{
  size_t total = (size_t)Op * Ip;
  for (size_t e = (size_t)blockIdx.x * 256 + threadIdx.x; e < total;
       e += (size_t)gridDim.x * 256) {
    int i = (int)(e % Ip);
    int o = (int)(e / Ip);
    float v = (o < Or && i < Ir) ? Win[(size_t)o * Ir + i] : 0.f;
    Wout[e] = __float2bfloat16(v);
  }
}

// ---------------- conv weights: f32 [O][Ir][3][3] -> bf16 [9][O][Ip] padded
__global__ void wtransbf_kernel(const float* __restrict__ Win,
                                __hip_bfloat16* __restrict__ Wout,
                                int O, int Ir, int Ip)
{
  size_t total = (size_t)9 * O * Ip;
  for (size_t e = (size_t)blockIdx.x * 256 + threadIdx.x; e < total;
       e += (size_t)gridDim.x * 256) {
    int i = (int)(e % Ip);
    size_t r = e / Ip;
    int o = (int)(r % O);
    int dydx = (int)(r / O);
    float v = (i < Ir) ? Win[((size_t)o * Ir + i) * 9 + dydx] : 0.f;
    Wout[e] = __float2bfloat16(v);
  }
}

// ---------------- MFMA 1x1 GEMM.  X: [B][N][Ip] bf16, Wb: [Opad][Ip] bf16.
// OMODE 0: f32 [B][N][O] + bf16 [B][N][O] (+bias); 1: bf16 [B][N][O] (+bias);
// 2: bf16 [B][O][N] (v-layout, swapped operands).
template<int OMODE>
__global__ __launch_bounds__(256, 3) void gemm3_kernel(
    const __hip_bfloat16* __restrict__ X, const __hip_bfloat16* __restrict__ Wb,
    const float* __restrict__ Bias, float* __restrict__ Yf,
    __hip_bfloat16* __restrict__ Yb, int Ip, int O)
{
  const int n0 = blockIdx.x * 64, o0 = blockIdx.y * 64, b = blockIdx.z;
  const int tid = threadIdx.x, wv = tid >> 6, lane = tid & 63;
  const int lg = lane >> 4, lr = lane & 15;
  __shared__ __align__(16) __hip_bfloat16 Xs[64 * 32];
  __shared__ __align__(16) __hip_bfloat16 Wsh[64 * 32];

  const int nn = tid >> 2, ig = tid & 3;
  const __hip_bfloat16* xrow = X + ((size_t)b * NPIX + n0 + nn) * Ip;
  const __hip_bfloat16* wrow = Wb + (size_t)(o0 + nn) * Ip;
  const int sw = 8 * (ig ^ (nn & 3));

  float4v acc[4];
#pragma unroll
  for (int f = 0; f < 4; ++f) acc[f] = (float4v){0.f, 0.f, 0.f, 0.f};

  const int nch = Ip >> 5;
  short8v xr_ = *(const short8v*)(xrow + sw);
  short8v wr_ = *(const short8v*)(wrow + sw);

  for (int ci = 0; ci < nch; ++ci) {
    __syncthreads();
    *(short8v*)(Xs  + nn * 32 + ig * 8) = xr_;
    *(short8v*)(Wsh + nn * 32 + ig * 8) = wr_;
    __syncthreads();
    if (ci + 1 < nch) {
      xr_ = *(const short8v*)(xrow + (ci + 1) * 32 + sw);
      wr_ = *(const short8v*)(wrow + (ci + 1) * 32 + sw);
    }
    if (OMODE < 2) {
      int ar = 16 * wv + lr;
      short8v a = *(const short8v*)(Xs + ar * 32 + 8 * (lg ^ (ar & 3)));
#pragma unroll
      for (int of = 0; of < 4; ++of) {
        int br = 16 * of + lr;
        short8v bb = *(const short8v*)(Wsh + br * 32 + 8 * (lg ^ (br & 3)));
        acc[of] = __builtin_amdgcn_mfma_f32_16x16x32_bf16(a, bb, acc[of], 0, 0, 0);
      }
    } else {
      int ar = 16 * wv + lr;
      short8v a = *(const short8v*)(Wsh + ar * 32 + 8 * (lg ^ (ar & 3)));
#pragma unroll
      for (int nf = 0; nf < 4; ++nf) {
        int br = 16 * nf + lr;
        short8v bb = *(const short8v*)(Xs + br * 32 + 8 * (lg ^ (br & 3)));
        acc[nf] = __builtin_amdgcn_mfma_f32_16x16x32_bf16(a, bb, acc[nf], 0, 0, 0);
      }
    }
  }

  if (OMODE < 2) {
#pragma unroll
    for (int r = 0; r < 4; ++r) {
      size_t row = (size_t)b * NPIX + n0 + 16 * wv + 4 * lg + r;
#pragma unroll
      for (int of = 0; of < 4; ++of) {
        int o = o0 + 16 * of + lr;
        if (o < O) {
          float v = acc[of][r] + (Bias ? Bias[o] : 0.f);
          if (OMODE == 0) Yf[row * O + o] = v;
          Yb[row * O + o] = __float2bfloat16(v);
        }
      }
    }
  } else {
#pragma unroll
    for (int r = 0; r < 4; ++r) {
      int c = o0 + 16 * wv + 4 * lg + r;
      if (c < O) {
#pragma unroll
        for (int nf = 0; nf < 4; ++nf) {
          int n = n0 + 16 * nf + lr;
          Yb[((size_t)b * O + c) * NPIX + n] = __float2bfloat16(acc[nf][r]);
        }
      }
    }
  }
}

// ---------------- flash attention, KV-split 2, bf16 MFMA, online softmax.
// Q,K: [B][N][C] bf16; V: [B][C][N] bf16. Writes unnormalized Opart bf16
// [2][B][N][C] and ml f32 [2][B][N][2].
template<int C>
__global__ __launch_bounds__(256, 2) void flash3_kernel(
    const __hip_bfloat16* __restrict__ Q, const __hip_bfloat16* __restrict__ K,
    const __hip_bfloat16* __restrict__ V,
    __hip_bfloat16* __restrict__ Opart, float* __restrict__ ml)
{
  constexpr int N = NPIX;
  constexpr int NC32 = C / 32;
  constexpr int NCF  = C / 16;
  constexpr int SPR  = C / 8;      // K LDS slots per row
  constexpr int NST  = C / 32;     // stage regs each (slots/256)
  const int n0 = blockIdx.x * 64;
  const int split = blockIdx.y;
  const int b = blockIdx.z;
  const int tid = threadIdx.x, w = tid >> 6, lane = tid & 63;
  const int lg = lane >> 4, lr = lane & 15;

  __shared__ __align__(16) __hip_bfloat16 Ks[64 * C];
  __shared__ __align__(16) __hip_bfloat16 Vs[C * 64];
  __shared__ __align__(16) __hip_bfloat16 Ps[4][64][16];

  short8v qf[NC32];
  {
    const __hip_bfloat16* qp = Q + ((size_t)b * N + n0 + 16 * w + lr) * C + 8 * lg;
#pragma unroll
    for (int ks = 0; ks < NC32; ++ks) qf[ks] = *(const short8v*)(qp + 32 * ks);
  }

  float4v oacc[NCF];
#pragma unroll
  for (int f = 0; f < NCF; ++f) oacc[f] = (float4v){0.f, 0.f, 0.f, 0.f};
  float mrun[4], lrun[4];
#pragma unroll
  for (int r = 0; r < 4; ++r) { mrun[r] = -INFINITY; lrun[r] = 0.f; }

  const __hip_bfloat16* Kb = K + (size_t)b * N * C;
  const __hip_bfloat16* Vb = V + (size_t)b * C * N;
  const int m0 = split * (N / 2);

  short8v kreg[NST], vreg[NST];
#pragma unroll
  for (int i = 0; i < NST; ++i) {
    int s = tid + i * 256;
    int row = s / SPR, c8i = s % SPR;
    kreg[i] = *(const short8v*)(Kb + (size_t)(m0 + row) * C + 8 * (c8i ^ (row & 3)));
  }
#pragma unroll
  for (int i = 0; i < NST; ++i) {
    int s = tid + i * 256;
    int c = s >> 3, m8i = s & 7;
    vreg[i] = *(const short8v*)(Vb + (size_t)c * N + m0 + 8 * (m8i ^ (c & 3)));
  }

  for (int t = 0; t < 32; ++t) {
    __syncthreads();
#pragma unroll
    for (int i = 0; i < NST; ++i) {
      int s = tid + i * 256;
      *(short8v*)(Ks + s * 8) = kreg[i];
      *(short8v*)(Vs + s * 8) = vreg[i];
    }
    __syncthreads();
    if (t < 31) {
      const int mn = m0 + (t + 1) * 64;
#pragma unroll
      for (int i = 0; i < NST; ++i) {
        int s = tid + i * 256;
        int row = s / SPR, c8i = s % SPR;
        kreg[i] = *(const short8v*)(Kb + (size_t)(mn + row) * C + 8 * (c8i ^ (row & 3)));
      }
#pragma unroll
      for (int i = 0; i < NST; ++i) {
        int s = tid + i * 256;
        int c = s >> 3, m8i = s & 7;
        vreg[i] = *(const short8v*)(Vb + (size_t)c * N + mn + 8 * (m8i ^ (c & 3)));
      }
    }
    // ---- S = Q^T K
    float4v sacc[4];
#pragma unroll
    for (int mf = 0; mf < 4; ++mf) sacc[mf] = (float4v){0.f, 0.f, 0.f, 0.f};
#pragma unroll
    for (int ks = 0; ks < NC32; ++ks)
#pragma unroll
      for (int mf = 0; mf < 4; ++mf) {
        int m = 16 * mf + lr;
        short8v k8 = *(const short8v*)(Ks + m * C + 32 * ks + 8 * (lg ^ (m & 3)));
        sacc[mf] = __builtin_amdgcn_mfma_f32_16x16x32_bf16(qf[ks], k8, sacc[mf], 0, 0, 0);
      }
    // ---- online softmax (rows n = 16w + 4lg + r)
    float scal[4];
#pragma unroll
    for (int r = 0; r < 4; ++r) {
      float pm = fmaxf(fmaxf(sacc[0][r], sacc[1][r]), fmaxf(sacc[2][r], sacc[3][r]));
#pragma unroll
      for (int off = 1; off < 16; off <<= 1) pm = fmaxf(pm, __shfl_xor(pm, off));
      float mnew = fmaxf(mrun[r], pm);
      float sc = __expf(mrun[r] - mnew);
      mrun[r] = mnew;
      float rs = 0.f, p[4];
#pragma unroll
      for (int mf = 0; mf < 4; ++mf) { p[mf] = __expf(sacc[mf][r] - mnew); rs += p[mf]; }
#pragma unroll
      for (int mf = 0; mf < 4; ++mf)
        Ps[mf][16 * w + 4 * lg + r][lr] = __float2bfloat16(p[mf]);
#pragma unroll
      for (int off = 1; off < 16; off <<= 1) rs += __shfl_xor(rs, off);
      lrun[r] = lrun[r] * sc + rs;
      scal[r] = sc;
    }
#pragma unroll
    for (int f = 0; f < NCF; ++f)
#pragma unroll
      for (int r = 0; r < 4; ++r) oacc[f][r] *= scal[r];

    asm volatile("s_waitcnt lgkmcnt(0)" ::: "memory");   // wave-private P RAW

    // ---- O += P V^T
    short8v pa0 = *(const short8v*)(&Ps[lg >> 1][16 * w + lr][8 * (lg & 1)]);
    short8v pa1 = *(const short8v*)(&Ps[2 + (lg >> 1)][16 * w + lr][8 * (lg & 1)]);
#pragma unroll
    for (int cf = 0; cf < NCF; ++cf) {
      int c = 16 * cf + lr;
      const __hip_bfloat16* vb = Vs + c * 64;
      short8v v0 = *(const short8v*)(vb + 8 * (lg ^ (c & 3)));
      short8v v1 = *(const short8v*)(vb + 32 + 8 * (lg ^ (c & 3)));
      oacc[cf] = __builtin_amdgcn_mfma_f32_16x16x32_bf16(pa0, v0, oacc[cf], 0, 0, 0);
      oacc[cf] = __builtin_amdgcn_mfma_f32_16x16x32_bf16(pa1, v1, oacc[cf], 0, 0, 0);
    }
  }
  // ---- epilogue: unnormalized partials, channel-last (coalesced)
  const size_t rbase = (size_t)(split * NB + b) * N;
#pragma unroll
  for (int r = 0; r < 4; ++r) {
    int n = n0 + 16 * w + 4 * lg + r;
    if (lr == 0) { ml[(rbase + n) * 2] = mrun[r]; ml[(rbase + n) * 2 + 1] = lrun[r]; }
#pragma unroll
    for (int cf = 0; cf < NCF; ++cf)
      Opart[(rbase + n) * C + 16 * cf + lr] = __float2bfloat16(oacc[cf][r]);
  }
}

// ---------------- merge 2 splits + gamma + residual -> t bf16 [B][N][C]
template<int C>
__global__ __launch_bounds__(256) void merge3_kernel(
    const __hip_bfloat16* __restrict__ Op, const float* __restrict__ ml,
    const float* __restrict__ R, const float* __restrict__ gamma_p,
    __hip_bfloat16* __restrict__ T)
{
  const size_t row = blockIdx.x;              // 16384 rows (split0 index)
  const size_t row1 = row + (size_t)NB * NPIX;
  float m0 = ml[row * 2],  l0 = ml[row * 2 + 1];
  float m1 = ml[row1 * 2], l1 = ml[row1 * 2 + 1];
  float m = fmaxf(m0, m1);
  float e0 = __expf(m0 - m), e1 = __expf(m1 - m);
  float rinv = gamma_p[0] / (l0 * e0 + l1 * e1);
  for (int c = threadIdx.x; c < C; c += 256) {
    float o = __bfloat162float(Op[row * C + c]) * e0 +
              __bfloat162float(Op[row1 * C + c]) * e1;
    T[row * C + c] = __float2bfloat16(o * rinv + R[row * C + c]);
  }
}

// ---------------- conv3x3 MFMA implicit GEMM. X: [B][N][IC] bf16 (chan-last),
// W2: [9][256][IC] bf16. Y: [B][N][256] f32. Block: 64 o x 64 w (one image row).
template<int IC>
__global__ __launch_bounds__(256, 2) void conv3_kernel(
    const __hip_bfloat16* __restrict__ X, const __hip_bfloat16* __restrict__ W2,
    float* __restrict__ Y)
{
  constexpr int NCH = IC / 32;
  constexpr int XP = 66 * 32;
  const int h = blockIdx.x, o0 = blockIdx.y * 64, b = blockIdx.z;
  const int tid = threadIdx.x, wv = tid >> 6, lane = tid & 63;
  const int lg = lane >> 4, lr = lane & 15;

  __shared__ __align__(16) __hip_bfloat16 Ws[9 * 64 * 32];
  __shared__ __align__(16) __hip_bfloat16 X3[3 * XP];

  for (int e = tid; e < 192; e += 256) {      // zero w-halo rows 0 and 65
    int p = e / 64, rr = (e >> 5) & 1, i = e & 31;
    X3[p * XP + (rr ? 65 * 32 : 0) + i] = __float2bfloat16(0.f);
  }

  float4v acc[4];
#pragma unroll
  for (int f = 0; f < 4; ++f) acc[f] = (float4v){0.f, 0.f, 0.f, 0.f};

  short8v xreg[3], wreg[9];
#define LOADX(CI)                                                              \
  _Pragma("unroll")                                                            \
  for (int j = 0; j < 3; ++j) {                                                \
    int s = tid + j * 256;                                                     \
    int dy = s >> 8, ww = (s >> 2) & 63, ig = s & 3;                           \
    int hs = h + dy - 1;                                                       \
    if (hs >= 0 && hs < 64)                                                    \
      xreg[j] = *(const short8v*)(X + ((size_t)b * NPIX + hs * 64 + ww) * IC + \
                                  (CI) * 32 + 8 * (ig ^ ((ww + 1) & 3)));      \
    else                                                                       \
      xreg[j] = (short8v){0, 0, 0, 0, 0, 0, 0, 0};                             \
  }
#define LOADW(CI)                                                              \
  _Pragma("unroll")                                                            \
  for (int j = 0; j < 9; ++j) {                                                \
    int s = tid + j * 256;                                                     \
    int dydx = s >> 8, oo = (s >> 2) & 63, ig = s & 3;                         \
    wreg[j] = *(const short8v*)(W2 + ((size_t)(dydx * 256 + o0 + oo)) * IC +   \
                                (CI) * 32 + 8 * (ig ^ (oo & 3)));              \
  }
  LOADX(0); LOADW(0);

  for (int ci = 0; ci < NCH; ++ci) {
    __syncthreads();
#pragma unroll
    for (int j = 0; j < 3; ++j) {
      int s = tid + j * 256;
      int dy = s >> 8, ww = (s >> 2) & 63, ig = s & 3;
      *(short8v*)(X3 + dy * XP + (ww + 1) * 32 + ig * 8) = xreg[j];
    }
#pragma unroll
    for (int j = 0; j < 9; ++j) {
      int s = tid + j * 256;
      *(short8v*)(Ws + s * 8) = wreg[j];
    }
    __syncthreads();
    if (ci + 1 < NCH) { LOADX(ci + 1); LOADW(ci + 1); }
#pragma unroll
    for (int dy = 0; dy < 3; ++dy)
#pragma unroll
      for (int dx = 0; dx < 3; ++dx) {
        int rs_ = 16 * wv + lr + dx;
        short8v a = *(const short8v*)(X3 + dy * XP + rs_ * 32 + 8 * (lg ^ (rs_ & 3)));
#pragma unroll
        for (int of = 0; of < 4; ++of) {
          int br = 16 * of + lr;
          short8v bb = *(const short8v*)(Ws + (dy * 3 + dx) * 2048 + br * 32 +
                                         8 * (lg ^ (br & 3)));
          acc[of] = __builtin_amdgcn_mfma_f32_16x16x32_bf16(a, bb, acc[of], 0, 0, 0);
        }
      }
  }
#pragma unroll
  for (int r = 0; r < 4; ++r) {
    size_t row = (size_t)b * NPIX + h * 64 + 16 * wv + 4 * lg + r;
#pragma unroll
    for (int of = 0; of < 4; ++of)
      Y[row * 256 + o0 + 16 * of + lr] = acc[of][r];
  }
#undef LOADX
#undef LOADW
}

// ---------------- BN stats, two-stage. X: [16384][256] f32.
__global__ __launch_bounds__(256) void stats1_kernel(
    const float* __restrict__ X, float* __restrict__ Part)
{
  const int o0 = (blockIdx.x & 3) * 64;
  const int rc = blockIdx.x >> 2;
  const int tid = threadIdx.x;
  const int o = o0 + (tid & 63), rq = tid >> 6;
  float s = 0.f, sq = 0.f;
  for (int rr = rq; rr < 256; rr += 4) {
    float v = X[(size_t)(rc * 256 + rr) * 256 + o];
    s += v; sq += v * v;
  }
  __shared__ float rs[256], rq2[256];
  rs[tid] = s; rq2[tid] = sq;
  __syncthreads();
  if (tid < 64) {
    s  = rs[tid] + rs[tid + 64] + rs[tid + 128] + rs[tid + 192];
    sq = rq2[tid] + rq2[tid + 64] + rq2[tid + 128] + rq2[tid + 192];
    Part[(o0 + tid) * 128 + rc * 2]     = s;
    Part[(o0 + tid) * 128 + rc * 2 + 1] = sq;
  }
}

__global__ __launch_bounds__(256) void stats2_kernel(
    const float* __restrict__ Part, float* __restrict__ Mean, float* __restrict__ Rstd)
{
  const int o = threadIdx.x;
  float s = 0.f, sq = 0.f;
  for (int rc = 0; rc < 64; ++rc) {
    s += Part[o * 128 + rc * 2];
    sq += Part[o * 128 + rc * 2 + 1];
  }
  float mean = s / 16384.f;
  float var = sq / 16384.f - mean * mean;
  Mean[o] = mean;
  Rstd[o] = 1.f / sqrtf(var + 1e-5f);
}

// ---------------- BN apply #1 + ReLU + cat flow -> cat f32/bf16 [16384][288]
__global__ __launch_bounds__(320) void bnapply1_kernel(
    const float* __restrict__ X, const float* __restrict__ Flow,
    const float* __restrict__ Mean, const float* __restrict__ Rstd,
    const float* __restrict__ G, const float* __restrict__ Bt,
    float* __restrict__ CatF, __hip_bfloat16* __restrict__ CatB)
{
  const size_t row = blockIdx.x;
  const int t = threadIdx.x;
  if (t >= 288) return;
  float val;
  if (t < 256) {
    float v = X[row * 256 + t];
    val = fmaxf((v - Mean[t]) * Rstd[t] * G[t] + Bt[t], 0.f);
  } else if (t < 258) {
    int b = (int)(row >> 12), n = (int)(row & 4095);
    val = Flow[((size_t)(b * 2 + (t - 256)) << 12) + n];
  } else val = 0.f;
  CatF[row * 288 + t] = val;
  CatB[row * 288 + t] = __float2bfloat16(val);
}

// ---------------- BN apply #2 + ReLU, in place on [16384][256] f32
__global__ __launch_bounds__(256) void bnapply2_kernel(
    float* X, const float* __restrict__ Mean, const float* __restrict__ Rstd,
    const float* __restrict__ G, const float* __restrict__ Bt)
{
  const size_t idx = (size_t)blockIdx.x * 256 + threadIdx.x;
  const int t = threadIdx.x;
  float v = X[idx];
  X[idx] = fmaxf((v - Mean[t]) * Rstd[t] * G[t] + Bt[t], 0.f);
}

// ---------------- pred: out[row] = dot(X[row][0:256], W) + bias
__global__ __launch_bounds__(256) void pred3_kernel(
    const float* __restrict__ X, const float* __restrict__ Wp,
    const float* __restrict__ Bp, float* __restrict__ Out)
{
  const int wv = threadIdx.x >> 6, lane = threadIdx.x & 63;
  const size_t row = (size_t)blockIdx.x * 4 + wv;
  const float* xr = X + row * 256;
  float acc = 0.f;
#pragma unroll
  for (int cc = 0; cc < 4; ++cc) acc = fmaf(xr[cc * 64 + lane], Wp[cc * 64 + lane], acc);
#pragma unroll
  for (int off = 1; off < 64; off <<= 1) acc += __shfl_xor(acc, off);
  if (lane == 0) Out[row] = acc + Bp[0];
}

// ============================================================================
extern "C" void kernel_launch(void* const* d_in, const int* in_sizes, int n_in,
                              void* d_out, int out_size, void* d_ws, size_t ws_size,
                              hipStream_t stream)
{
  (void)in_sizes; (void)n_in; (void)out_size; (void)ws_size;
  const float* x      = (const float*)d_in[0];
  const float* y      = (const float*)d_in[1];
  const float* flow   = (const float*)d_in[2];
  const float* w1x1   = (const float*)d_in[3];
  const float* b1x1   = (const float*)d_in[4];
  const float* ca_wq  = (const float*)d_in[5];
  const float* ca_wk  = (const float*)d_in[6];
  const float* ca_wv  = (const float*)d_in[7];
  const float* ca_g   = (const float*)d_in[8];
  const float* cbr1_w = (const float*)d_in[9];
  const float* bn1_g  = (const float*)d_in[10];
  const float* bn1_b  = (const float*)d_in[11];
  const float* sa_wq  = (const float*)d_in[12];
  const float* sa_wk  = (const float*)d_in[13];
  const float* sa_wv  = (const float*)d_in[14];
  const float* sa_g   = (const float*)d_in[15];
  const float* cbr2_w = (const float*)d_in[16];
  const float* bn2_g  = (const float*)d_in[17];
  const float* bn2_b  = (const float*)d_in[18];
  const float* pred_w = (const float*)d_in[19];
  const float* pred_b = (const float*)d_in[20];
  float* out = (float*)d_out;

  // ---- workspace layout (float units)
  const size_t FSZ = (size_t)NB * NPIX * 288;       // 4,718,592 floats
  const size_t SSZ = FSZ / 2;                       // bf16 slot, 2,359,296 floats
  float* ws = (float*)d_ws;
  float* F0 = ws;                 // xT -> Opart1 -> conv1out -> Opart2 -> conv2out/bn2
  float* F1 = ws + FSZ;           // yT -> cat f32
  float* F2 = ws + 2 * FSZ;       // xb f32 (flash1 residual)
  float* Sb = ws + 3 * FSZ;
  __hip_bfloat16* S0 = (__hip_bfloat16*)(Sb);            // xb_bf -> t -> q2
  __hip_bfloat16* S1 = (__hip_bfloat16*)(Sb + SSZ);      // yb_bf -> k2
  __hip_bfloat16* S2 = (__hip_bfloat16*)(Sb + 2 * SSZ);  // q -> v2
  __hip_bfloat16* S3 = (__hip_bfloat16*)(Sb + 3 * SSZ);  // k -> catT
  __hip_bfloat16* S4 = (__hip_bfloat16*)(Sb + 4 * SSZ);  // v -> t2
  float* Wr = Sb + 5 * SSZ;
  __hip_bfloat16* w1bf  = (__hip_bfloat16*)Wr;                       // 256x512
  __hip_bfloat16* caqb  = w1bf + (size_t)256 * 512;                  // 256x256
  __hip_bfloat16* cakb  = caqb + (size_t)256 * 256;
  __hip_bfloat16* cavb  = cakb + (size_t)256 * 256;
  __hip_bfloat16* saqb  = cavb + (size_t)256 * 256;                  // 320x288
  __hip_bfloat16* sakb  = saqb + (size_t)320 * 288;
  __hip_bfloat16* savb  = sakb + (size_t)320 * 288;
  __hip_bfloat16* w2abf = savb + (size_t)320 * 288;                  // 9x256x256
  __hip_bfloat16* w2bbf = w2abf + (size_t)9 * 256 * 256;             // 9x256x288
  float* Part = (float*)(w2bbf + (size_t)9 * 256 * 288);             // 32768
  float* Mean = Part + 32768;                                        // 256
  float* Rstd = Mean + 256;                                          // 256
  float* Mlb  = Rstd + 256;                                          // 131072

  __hip_bfloat16* xT = (__hip_bfloat16*)F0;
  __hip_bfloat16* yT = (__hip_bfloat16*)F1;
  __hip_bfloat16* Op = (__hip_bfloat16*)F0;   // flash partials (reused)

  dim3 blk(256);

  // ---- weight prep
  wprep_kernel<<<dim3(256), blk, 0, stream>>>(w1x1, w1bf, 256, 512, 256, 512);
  wprep_kernel<<<dim3(256), blk, 0, stream>>>(ca_wq, caqb, 256, 256, 256, 256);
  wprep_kernel<<<dim3(256), blk, 0, stream>>>(ca_wk, cakb, 256, 256, 256, 256);
  wprep_kernel<<<dim3(256), blk, 0, stream>>>(ca_wv, cavb, 256, 256, 256, 256);
  wprep_kernel<<<dim3(256), blk, 0, stream>>>(sa_wq, saqb, 258, 258, 320, 288);
  wprep_kernel<<<dim3(256), blk, 0, stream>>>(sa_wk, sakb, 258, 258, 320, 288);
  wprep_kernel<<<dim3(256), blk, 0, stream>>>(sa_wv, savb, 258, 258, 320, 288);
  wtransbf_kernel<<<dim3(512), blk, 0, stream>>>(cbr1_w, w2abf, 256, 256, 256);
  wtransbf_kernel<<<dim3(512), blk, 0, stream>>>(cbr2_w, w2bbf, 256, 258, 288);

  // ---- transpose inputs to channel-last bf16
  transp_kernel<<<dim3(8, 64, 4), blk, 0, stream>>>(x, xT);
  transp_kernel<<<dim3(8, 64, 4), blk, 0, stream>>>(y, yT);

  // ---- xb (f32 + bf16), yb (bf16)
  gemm3_kernel<0><<<dim3(64, 4, 4), blk, 0, stream>>>(xT, w1bf, b1x1, F2, S0, 512, 256);
  gemm3_kernel<1><<<dim3(64, 4, 4), blk, 0, stream>>>(yT, w1bf, b1x1, nullptr, S1, 512, 256);

  // ---- cross q,k,v
  gemm3_kernel<1><<<dim3(64, 4, 4), blk, 0, stream>>>(S0, caqb, nullptr, nullptr, S2, 256, 256);
  gemm3_kernel<1><<<dim3(64, 4, 4), blk, 0, stream>>>(S1, cakb, nullptr, nullptr, S3, 256, 256);
  gemm3_kernel<2><<<dim3(64, 4, 4), blk, 0, stream>>>(S1, cavb, nullptr, nullptr, S4, 256, 256);

  // ---- cross flash (+merge: t = gamma*attn + xb -> S0 bf16 [n][256])
  flash3_kernel<256><<<dim3(64, 2, 4), blk, 0, stream>>>(S2, S3, S4, Op, Mlb);
  merge3_kernel<256><<<dim3(16384), blk, 0, stream>>>(Op, Mlb, F2, ca_g, S0);

  // ---- conv1 + BN + ReLU + cat
  conv3_kernel<256><<<dim3(64, 4, 4), blk, 0, stream>>>(S0, w2abf, F0);
  stats1_kernel<<<dim3(256), blk, 0, stream>>>(F0, Part);
  stats2_kernel<<<dim3(1), blk, 0, stream>>>(Part, Mean, Rstd);
  bnapply1_kernel<<<dim3(16384), dim3(320), 0, stream>>>(F0, flow, Mean, Rstd,
                                                         bn1_g, bn1_b, F1, S3);

  // ---- self q2,k2,v2 (C=288 padded, weights padded to 320 rows)
  gemm3_kernel<1><<<dim3(64, 5, 4), blk, 0, stream>>>(S3, saqb, nullptr, nullptr, S0, 288, 288);
  gemm3_kernel<1><<<dim3(64, 5, 4), blk, 0, stream>>>(S3, sakb, nullptr, nullptr, S1, 288, 288);
  gemm3_kernel<2><<<dim3(64, 5, 4), blk, 0, stream>>>(S3, savb, nullptr, nullptr, S2, 288, 288);

  // ---- self flash (+merge: t2 -> S4 bf16 [n][288])
  flash3_kernel<288><<<dim3(64, 2, 4), blk, 0, stream>>>(S0, S1, S2, Op, Mlb);
  merge3_kernel<288><<<dim3(16384), blk, 0, stream>>>(Op, Mlb, F1, sa_g, S4);

  // ---- conv2 + BN + ReLU (in place), pred
  conv3_kernel<288><<<dim3(64, 4, 4), blk, 0, stream>>>(S4, w2bbf, F0);
  stats1_kernel<<<dim3(256), blk, 0, stream>>>(F0, Part);
  stats2_kernel<<<dim3(1), blk, 0, stream>>>(Part, Mean, Rstd);
  bnapply2_kernel<<<dim3(16384), blk, 0, stream>>>(F0, Mean, Rstd, bn2_g, bn2_b);

  pred3_kernel<<<dim3(4096), blk, 0, stream>>>(F0, pred_w, pred_b, out);
}

// Round 5
// 545.039 us; speedup vs baseline: 13.7284x; 1.1475x over previous
//
#include <hip/hip_runtime.h>
#include <hip/hip_bf16.h>
#include <math.h>

// ============================================================================
// Round 4: flash4 = chunked conflict-free LDS + global_load_lds staging +
// q-register-blocking. Rest of pipeline unchanged from round 3.
// ============================================================================

#define NPIX 4096
#define NB   4

typedef __attribute__((ext_vector_type(8))) short short8v;
typedef __attribute__((ext_vector_type(4))) float float4v;

__device__ __forceinline__ short f2bs(float f) {
  __hip_bfloat16 h = __float2bfloat16(f);
  short r; __builtin_memcpy(&r, &h, 2); return r;
}

__device__ __forceinline__ void glld16(const void* g, void* l) {
  __builtin_amdgcn_global_load_lds(
      (const __attribute__((address_space(1))) unsigned int*)g,
      (__attribute__((address_space(3))) unsigned int*)l, 16, 0, 0);
}

// ---------------- transpose: x [B][512][N] f32 -> xT [B][N][512] bf16
__global__ __launch_bounds__(256) void transp_kernel(
    const float* __restrict__ X, __hip_bfloat16* __restrict__ XT)
{
  const int i0 = blockIdx.x * 64, n0 = blockIdx.y * 64, b = blockIdx.z;
  const int tid = threadIdx.x;
  __shared__ float Ls[64][68];
#pragma unroll
  for (int it = 0; it < 4; ++it) {
    int ir = it * 16 + (tid >> 4);
    int nc = (tid & 15) * 4;
    float4 v = *(const float4*)(X + ((size_t)b * 512 + i0 + ir) * NPIX + n0 + nc);
    *(float4*)(&Ls[ir][nc]) = v;
  }
  __syncthreads();
#pragma unroll
  for (int ot = 0; ot < 2; ++ot) {
    int n = ot * 32 + (tid >> 3);
    int ig = tid & 7;
    short8v o;
#pragma unroll
    for (int j = 0; j < 8; ++j) o[j] = f2bs(Ls[8 * ig + j][n]);
    *(short8v*)(XT + ((size_t)b * NPIX + n0 + n) * 512 + i0 + 8 * ig) = o;
  }
}

// ---------------- weight prep: f32 [Or][Ir] -> bf16 [Op][Ip] zero-padded
__global__ void wprep_kernel(const float* __restrict__ Win,
                             __hip_bfloat16* __restrict__ Wout,
                             int Or, int Ir, int Op, int Ip)
{
  size_t total = (size_t)Op * Ip;
  for (size_t e = (size_t)blockIdx.x * 256 + threadIdx.x; e < total;
       e += (size_t)gridDim.x * 256) {
    int i = (int)(e % Ip);
    int o = (int)(e / Ip);
    float v = (o < Or && i < Ir) ? Win[(size_t)o * Ir + i] : 0.f;
    Wout[e] = __float2bfloat16(v);
  }
}

// ---------------- conv weights: f32 [O][Ir][3][3] -> bf16 [9][O][Ip] padded
__global__ void wtransbf_kernel(const float* __restrict__ Win,
                                __hip_bfloat16* __restrict__ Wout,
                                int O, int Ir, int Ip)
{
  size_t total = (size_t)9 * O * Ip;
  for (size_t e = (size_t)blockIdx.x * 256 + threadIdx.x; e < total;
       e += (size_t)gridDim.x * 256) {
    int i = (int)(e % Ip);
    size_t r = e / Ip;
    int o = (int)(r % O);
    int dydx = (int)(r / O);
    float v = (i < Ir) ? Win[((size_t)o * Ir + i) * 9 + dydx] : 0.f;
    Wout[e] = __float2bfloat16(v);
  }
}

// ---------------- MFMA 1x1 GEMM.  X: [B][N][Ip] bf16, Wb: [Opad][Ip] bf16.
// OMODE 0: f32 [B][N][O] + bf16 [B][N][O] (+bias)
// OMODE 1: bf16 [B][N][O] (+bias)
// OMODE 3: bf16 K-chunk layout [B][O/8][N][8]
// OMODE 4: bf16 V-chunk layout [B][N/8][O][8] (swapped operands)
template<int OMODE>
__global__ __launch_bounds__(256, 3) void gemm3_kernel(
    const __hip_bfloat16* __restrict__ X, const __hip_bfloat16* __restrict__ Wb,
    const float* __restrict__ Bias, float* __restrict__ Yf,
    __hip_bfloat16* __restrict__ Yb, int Ip, int O)
{
  const int n0 = blockIdx.x * 64, o0 = blockIdx.y * 64, b = blockIdx.z;
  const int tid = threadIdx.x, wv = tid >> 6, lane = tid & 63;
  const int lg = lane >> 4, lr = lane & 15;
  __shared__ __align__(16) __hip_bfloat16 Xs[64 * 32];
  __shared__ __align__(16) __hip_bfloat16 Wsh[64 * 32];

  const int nn = tid >> 2, ig = tid & 3;
  const __hip_bfloat16* xrow = X + ((size_t)b * NPIX + n0 + nn) * Ip;
  const __hip_bfloat16* wrow = Wb + (size_t)(o0 + nn) * Ip;
  const int sw = 8 * (ig ^ (nn & 3));

  float4v acc[4];
#pragma unroll
  for (int f = 0; f < 4; ++f) acc[f] = (float4v){0.f, 0.f, 0.f, 0.f};

  const int nch = Ip >> 5;
  short8v xr_ = *(const short8v*)(xrow + sw);
  short8v wr_ = *(const short8v*)(wrow + sw);

  for (int ci = 0; ci < nch; ++ci) {
    __syncthreads();
    *(short8v*)(Xs  + nn * 32 + ig * 8) = xr_;
    *(short8v*)(Wsh + nn * 32 + ig * 8) = wr_;
    __syncthreads();
    if (ci + 1 < nch) {
      xr_ = *(const short8v*)(xrow + (ci + 1) * 32 + sw);
      wr_ = *(const short8v*)(wrow + (ci + 1) * 32 + sw);
    }
    if (OMODE != 4) {
      int ar = 16 * wv + lr;
      short8v a = *(const short8v*)(Xs + ar * 32 + 8 * (lg ^ (ar & 3)));
#pragma unroll
      for (int of = 0; of < 4; ++of) {
        int br = 16 * of + lr;
        short8v bb = *(const short8v*)(Wsh + br * 32 + 8 * (lg ^ (br & 3)));
        acc[of] = __builtin_amdgcn_mfma_f32_16x16x32_bf16(a, bb, acc[of], 0, 0, 0);
      }
    } else {
      int ar = 16 * wv + lr;
      short8v a = *(const short8v*)(Wsh + ar * 32 + 8 * (lg ^ (ar & 3)));
#pragma unroll
      for (int nf = 0; nf < 4; ++nf) {
        int br = 16 * nf + lr;
        short8v bb = *(const short8v*)(Xs + br * 32 + 8 * (lg ^ (br & 3)));
        acc[nf] = __builtin_amdgcn_mfma_f32_16x16x32_bf16(a, bb, acc[nf], 0, 0, 0);
      }
    }
  }

  if (OMODE < 2) {
#pragma unroll
    for (int r = 0; r < 4; ++r) {
      size_t row = (size_t)b * NPIX + n0 + 16 * wv + 4 * lg + r;
#pragma unroll
      for (int of = 0; of < 4; ++of) {
        int o = o0 + 16 * of + lr;
        if (o < O) {
          float v = acc[of][r] + (Bias ? Bias[o] : 0.f);
          if (OMODE == 0) Yf[row * O + o] = v;
          Yb[row * O + o] = __float2bfloat16(v);
        }
      }
    }
  } else if (OMODE == 3) {
    __hip_bfloat16* Hb = Yb + (size_t)b * NPIX * O;
#pragma unroll
    for (int r = 0; r < 4; ++r) {
      size_t n = n0 + 16 * wv + 4 * lg + r;
#pragma unroll
      for (int of = 0; of < 4; ++of) {
        int o = o0 + 16 * of + lr;
        if (o < O)
          Hb[((size_t)(o >> 3) * NPIX + n) * 8 + (o & 7)] = __float2bfloat16(acc[of][r]);
      }
    }
  } else {  // OMODE 4
    __hip_bfloat16* Hb = Yb + (size_t)b * NPIX * O;
#pragma unroll
    for (int r = 0; r < 4; ++r) {
      int c = o0 + 16 * wv + 4 * lg + r;
      if (c < O) {
#pragma unroll
        for (int nf = 0; nf < 4; ++nf) {
          int n = n0 + 16 * nf + lr;
          Hb[((size_t)(n >> 3) * O + c) * 8 + (n & 7)] = __float2bfloat16(acc[nf][r]);
        }
      }
    }
  }
}

// ---------------- flash4: conflict-free chunked LDS + global_load_lds.
// Q: [B][N][C].  K: [B][C/8][N][8].  V: [B][N/8][C][8].
// Block 256 thr (4 waves), each wave QB=16*RF q-rows. KV-split S.
// Writes unnormalized Opart bf16 [S][B][N][C], ml f32 [S][B][N][2].
template<int C, int RF, int S>
__global__ __launch_bounds__(256, 2) void flash4_kernel(
    const __hip_bfloat16* __restrict__ Q, const __hip_bfloat16* __restrict__ K,
    const __hip_bfloat16* __restrict__ V,
    __hip_bfloat16* __restrict__ Opart, float* __restrict__ ml)
{
  constexpr int N    = NPIX;
  constexpr int NC32 = C / 32;
  constexpr int NCF  = C / 16;
  constexpr int QB   = 16 * RF;
  constexpr int KBYTES = 128 * C;          // [C/8][64][8] bf16
  constexpr int NT   = (N / S) / 64;

  __shared__ __align__(1024) char smem[256 * C];
  __hip_bfloat16* Ks = (__hip_bfloat16*)smem;              // [C/8][64][8]
  __hip_bfloat16* Vs = (__hip_bfloat16*)(smem + KBYTES);   // [8][C][8]
  __hip_bfloat16* Ps = (__hip_bfloat16*)smem;              // alias: [4][QB][72]

  const int n0 = blockIdx.x * (4 * QB);
  const int split = blockIdx.y, b = blockIdx.z;
  const int tid = threadIdx.x, w = tid >> 6, lane = tid & 63;
  const int lg = lane >> 4, lr = lane & 15;

  const __hip_bfloat16* Kb = K + (size_t)b * N * C;
  const __hip_bfloat16* Vb = V + (size_t)b * N * C;

  // Q fragments (persistent)
  short8v qf[RF][NC32];
#pragma unroll
  for (int rf = 0; rf < RF; ++rf) {
    const __hip_bfloat16* qp =
        Q + ((size_t)b * N + n0 + QB * w + 16 * rf + lr) * C + 8 * lg;
#pragma unroll
    for (int ks = 0; ks < NC32; ++ks) qf[rf][ks] = *(const short8v*)(qp + 32 * ks);
  }

  float4v oacc[RF][NCF];
#pragma unroll
  for (int rf = 0; rf < RF; ++rf)
#pragma unroll
    for (int f = 0; f < NCF; ++f) oacc[rf][f] = (float4v){0.f, 0.f, 0.f, 0.f};
  float mrun[RF][4], lrun[RF][4];
#pragma unroll
  for (int rf = 0; rf < RF; ++rf)
#pragma unroll
    for (int r = 0; r < 4; ++r) { mrun[rf][r] = -INFINITY; lrun[rf][r] = 0.f; }

  const int m0base = split * (N / S);

  for (int t = 0; t < NT; ++t) {
    const int m0 = m0base + t * 64;
    __syncthreads();                       // prev-tile LDS reads complete
    // ---- stage K: LDS slot (c8, m) <- global chunk (c8, m0+m); lane = m
    for (int u = w; u < C / 8; u += 4)
      glld16(Kb + ((size_t)u * N + m0 + lane) * 8, Ks + u * 512);
    // ---- stage V: LDS slot (kv8, c) <- global chunk (m0/8+kv8, c)
    for (int u = w; u < C / 8; u += 4) {
      int s = u * 64 + lane;
      int kv8 = s / C, c = s % C;          // per-lane source
      glld16(Vb + ((size_t)(m0 / 8 + kv8) * C + c) * 8, Vs + u * 512);
    }
    asm volatile("s_waitcnt vmcnt(0)" ::: "memory");
    __syncthreads();                       // staging visible to all waves

    // ---- S = Q^T K
    float4v sacc[RF][4];
#pragma unroll
    for (int rf = 0; rf < RF; ++rf)
#pragma unroll
      for (int mf = 0; mf < 4; ++mf) sacc[rf][mf] = (float4v){0.f, 0.f, 0.f, 0.f};
    __builtin_amdgcn_s_setprio(1);
#pragma unroll
    for (int ks = 0; ks < NC32; ++ks)
#pragma unroll
      for (int mf = 0; mf < 4; ++mf) {
        short8v kf = *(const short8v*)(Ks + ((4 * ks + lg) * 64 + 16 * mf + lr) * 8);
#pragma unroll
        for (int rf = 0; rf < RF; ++rf)
          sacc[rf][mf] =
              __builtin_amdgcn_mfma_f32_16x16x32_bf16(qf[rf][ks], kf, sacc[rf][mf], 0, 0, 0);
      }
    __builtin_amdgcn_s_setprio(0);
    __syncthreads();                       // K reads done before P writes (alias)

    // ---- online softmax; write P (wave-private rows)
    float scal[RF][4];
#pragma unroll
    for (int rf = 0; rf < RF; ++rf)
#pragma unroll
      for (int r = 0; r < 4; ++r) {
        float pm = fmaxf(fmaxf(sacc[rf][0][r], sacc[rf][1][r]),
                         fmaxf(sacc[rf][2][r], sacc[rf][3][r]));
#pragma unroll
        for (int off = 1; off < 16; off <<= 1) pm = fmaxf(pm, __shfl_xor(pm, off));
        float mnew = fmaxf(mrun[rf][r], pm);
        float sc = __expf(mrun[rf][r] - mnew);
        mrun[rf][r] = mnew;
        float rs = 0.f;
#pragma unroll
        for (int mf = 0; mf < 4; ++mf) {
          float p = __expf(sacc[rf][mf][r] - mnew);
          rs += p;
          Ps[(size_t)(w * QB + 16 * rf + 4 * lg + r) * 72 + 16 * mf + lr] =
              __float2bfloat16(p);
        }
#pragma unroll
        for (int off = 1; off < 16; off <<= 1) rs += __shfl_xor(rs, off);
        lrun[rf][r] = lrun[rf][r] * sc + rs;
        scal[rf][r] = sc;
      }
#pragma unroll
    for (int rf = 0; rf < RF; ++rf)
#pragma unroll
      for (int f = 0; f < NCF; ++f)
#pragma unroll
        for (int r = 0; r < 4; ++r) oacc[rf][f][r] *= scal[rf][r];

    asm volatile("s_waitcnt lgkmcnt(0)" ::: "memory");  // wave-private P RAW

    // ---- O += P V^T
    short8v pa[RF][2];
#pragma unroll
    for (int rf = 0; rf < RF; ++rf)
#pragma unroll
      for (int h = 0; h < 2; ++h)
        pa[rf][h] = *(const short8v*)(Ps + (size_t)(w * QB + 16 * rf + lr) * 72 +
                                      32 * h + 8 * lg);
    __builtin_amdgcn_s_setprio(1);
#pragma unroll
    for (int cf = 0; cf < NCF; ++cf)
#pragma unroll
      for (int h = 0; h < 2; ++h) {
        short8v vf = *(const short8v*)(Vs + ((h * 4 + lg) * C + 16 * cf + lr) * 8);
#pragma unroll
        for (int rf = 0; rf < RF; ++rf)
          oacc[rf][cf] =
              __builtin_amdgcn_mfma_f32_16x16x32_bf16(pa[rf][h], vf, oacc[rf][cf], 0, 0, 0);
      }
    __builtin_amdgcn_s_setprio(0);
  }

  // ---- epilogue: unnormalized partials, channel-last
  const size_t rbase = (size_t)(split * NB + b) * N;
#pragma unroll
  for (int rf = 0; rf < RF; ++rf)
#pragma unroll
    for (int r = 0; r < 4; ++r) {
      int n = n0 + QB * w + 16 * rf + 4 * lg + r;
      if (lr == 0) {
        ml[(rbase + n) * 2]     = mrun[rf][r];
        ml[(rbase + n) * 2 + 1] = lrun[rf][r];
      }
#pragma unroll
      for (int cf = 0; cf < NCF; ++cf)
        Opart[(rbase + n) * C + 16 * cf + lr] = __float2bfloat16(oacc[rf][cf][r]);
    }
}

// ---------------- merge S splits + gamma + residual -> t bf16 [B][N][C]
template<int C, int S>
__global__ __launch_bounds__(256) void merge4_kernel(
    const __hip_bfloat16* __restrict__ Op, const float* __restrict__ ml,
    const float* __restrict__ R, const float* __restrict__ gamma_p,
    __hip_bfloat16* __restrict__ T)
{
  const size_t row = blockIdx.x;           // 16384 rows
  float m = -INFINITY;
#pragma unroll
  for (int s = 0; s < S; ++s)
    m = fmaxf(m, ml[((size_t)s * NB * NPIX + row) * 2]);
  float e[S]; float L = 0.f;
#pragma unroll
  for (int s = 0; s < S; ++s) {
    e[s] = __expf(ml[((size_t)s * NB * NPIX + row) * 2] - m);
    L += ml[((size_t)s * NB * NPIX + row) * 2 + 1] * e[s];
  }
  float rinv = gamma_p[0] / L;
  for (int c = threadIdx.x; c < C; c += 256) {
    float o = 0.f;
#pragma unroll
    for (int s = 0; s < S; ++s)
      o += __bfloat162float(Op[((size_t)s * NB * NPIX + row) * C + c]) * e[s];
    T[row * C + c] = __float2bfloat16(o * rinv + R[row * C + c]);
  }
}

// ---------------- conv3x3 MFMA implicit GEMM (unchanged from round 3)
template<int IC>
__global__ __launch_bounds__(256, 2) void conv3_kernel(
    const __hip_bfloat16* __restrict__ X, const __hip_bfloat16* __restrict__ W2,
    float* __restrict__ Y)
{
  constexpr int NCH = IC / 32;
  constexpr int XP = 66 * 32;
  const int h = blockIdx.x, o0 = blockIdx.y * 64, b = blockIdx.z;
  const int tid = threadIdx.x, wv = tid >> 6, lane = tid & 63;
  const int lg = lane >> 4, lr = lane & 15;

  __shared__ __align__(16) __hip_bfloat16 Ws[9 * 64 * 32];
  __shared__ __align__(16) __hip_bfloat16 X3[3 * XP];

  for (int e = tid; e < 192; e += 256) {
    int p = e / 64, rr = (e >> 5) & 1, i = e & 31;
    X3[p * XP + (rr ? 65 * 32 : 0) + i] = __float2bfloat16(0.f);
  }

  float4v acc[4];
#pragma unroll
  for (int f = 0; f < 4; ++f) acc[f] = (float4v){0.f, 0.f, 0.f, 0.f};

  short8v xreg[3], wreg[9];
#define LOADX(CI)                                                              \
  _Pragma("unroll")                                                            \
  for (int j = 0; j < 3; ++j) {                                                \
    int s = tid + j * 256;                                                     \
    int dy = s >> 8, ww = (s >> 2) & 63, ig = s & 3;                           \
    int hs = h + dy - 1;                                                       \
    if (hs >= 0 && hs < 64)                                                    \
      xreg[j] = *(const short8v*)(X + ((size_t)b * NPIX + hs * 64 + ww) * IC + \
                                  (CI) * 32 + 8 * (ig ^ ((ww + 1) & 3)));      \
    else                                                                       \
      xreg[j] = (short8v){0, 0, 0, 0, 0, 0, 0, 0};                             \
  }
#define LOADW(CI)                                                              \
  _Pragma("unroll")                                                            \
  for (int j = 0; j < 9; ++j) {                                                \
    int s = tid + j * 256;                                                     \
    int dydx = s >> 8, oo = (s >> 2) & 63, ig = s & 3;                         \
    wreg[j] = *(const short8v*)(W2 + ((size_t)(dydx * 256 + o0 + oo)) * IC +   \
                                (CI) * 32 + 8 * (ig ^ (oo & 3)));              \
  }
  LOADX(0); LOADW(0);

  for (int ci = 0; ci < NCH; ++ci) {
    __syncthreads();
#pragma unroll
    for (int j = 0; j < 3; ++j) {
      int s = tid + j * 256;
      int dy = s >> 8, ww = (s >> 2) & 63, ig = s & 3;
      *(short8v*)(X3 + dy * XP + (ww + 1) * 32 + ig * 8) = xreg[j];
    }
#pragma unroll
    for (int j = 0; j < 9; ++j) {
      int s = tid + j * 256;
      *(short8v*)(Ws + s * 8) = wreg[j];
    }
    __syncthreads();
    if (ci + 1 < NCH) { LOADX(ci + 1); LOADW(ci + 1); }
#pragma unroll
    for (int dy = 0; dy < 3; ++dy)
#pragma unroll
      for (int dx = 0; dx < 3; ++dx) {
        int rs_ = 16 * wv + lr + dx;
        short8v a = *(const short8v*)(X3 + dy * XP + rs_ * 32 + 8 * (lg ^ (rs_ & 3)));
#pragma unroll
        for (int of = 0; of < 4; ++of) {
          int br = 16 * of + lr;
          short8v bb = *(const short8v*)(Ws + (dy * 3 + dx) * 2048 + br * 32 +
                                         8 * (lg ^ (br & 3)));
          acc[of] = __builtin_amdgcn_mfma_f32_16x16x32_bf16(a, bb, acc[of], 0, 0, 0);
        }
      }
  }
#pragma unroll
  for (int r = 0; r < 4; ++r) {
    size_t row = (size_t)b * NPIX + h * 64 + 16 * wv + 4 * lg + r;
#pragma unroll
    for (int of = 0; of < 4; ++of)
      Y[row * 256 + o0 + 16 * of + lr] = acc[of][r];
  }
#undef LOADX
#undef LOADW
}

// ---------------- BN stats, two-stage. X: [16384][256] f32.
__global__ __launch_bounds__(256) void stats1_kernel(
    const float* __restrict__ X, float* __restrict__ Part)
{
  const int o0 = (blockIdx.x & 3) * 64;
  const int rc = blockIdx.x >> 2;
  const int tid = threadIdx.x;
  const int o = o0 + (tid & 63), rq = tid >> 6;
  float s = 0.f, sq = 0.f;
  for (int rr = rq; rr < 256; rr += 4) {
    float v = X[(size_t)(rc * 256 + rr) * 256 + o];
    s += v; sq += v * v;
  }
  __shared__ float rs[256], rq2[256];
  rs[tid] = s; rq2[tid] = sq;
  __syncthreads();
  if (tid < 64) {
    s  = rs[tid] + rs[tid + 64] + rs[tid + 128] + rs[tid + 192];
    sq = rq2[tid] + rq2[tid + 64] + rq2[tid + 128] + rq2[tid + 192];
    Part[(o0 + tid) * 128 + rc * 2]     = s;
    Part[(o0 + tid) * 128 + rc * 2 + 1] = sq;
  }
}

__global__ __launch_bounds__(256) void stats2_kernel(
    const float* __restrict__ Part, float* __restrict__ Mean, float* __restrict__ Rstd)
{
  const int o = threadIdx.x;
  float s = 0.f, sq = 0.f;
  for (int rc = 0; rc < 64; ++rc) {
    s += Part[o * 128 + rc * 2];
    sq += Part[o * 128 + rc * 2 + 1];
  }
  float mean = s / 16384.f;
  float var = sq / 16384.f - mean * mean;
  Mean[o] = mean;
  Rstd[o] = 1.f / sqrtf(var + 1e-5f);
}

// ---------------- BN apply #1 + ReLU + cat flow -> cat f32/bf16 [16384][288]
__global__ __launch_bounds__(320) void bnapply1_kernel(
    const float* __restrict__ X, const float* __restrict__ Flow,
    const float* __restrict__ Mean, const float* __restrict__ Rstd,
    const float* __restrict__ G, const float* __restrict__ Bt,
    float* __restrict__ CatF, __hip_bfloat16* __restrict__ CatB)
{
  const size_t row = blockIdx.x;
  const int t = threadIdx.x;
  if (t >= 288) return;
  float val;
  if (t < 256) {
    float v = X[row * 256 + t];
    val = fmaxf((v - Mean[t]) * Rstd[t] * G[t] + Bt[t], 0.f);
  } else if (t < 258) {
    int b = (int)(row >> 12), n = (int)(row & 4095);
    val = Flow[((size_t)(b * 2 + (t - 256)) << 12) + n];
  } else val = 0.f;
  CatF[row * 288 + t] = val;
  CatB[row * 288 + t] = __float2bfloat16(val);
}

// ---------------- BN apply #2 + ReLU, in place on [16384][256] f32
__global__ __launch_bounds__(256) void bnapply2_kernel(
    float* X, const float* __restrict__ Mean, const float* __restrict__ Rstd,
    const float* __restrict__ G, const float* __restrict__ Bt)
{
  const size_t idx = (size_t)blockIdx.x * 256 + threadIdx.x;
  const int t = threadIdx.x;
  float v = X[idx];
  X[idx] = fmaxf((v - Mean[t]) * Rstd[t] * G[t] + Bt[t], 0.f);
}

// ---------------- pred: out[row] = dot(X[row][0:256], W) + bias
__global__ __launch_bounds__(256) void pred3_kernel(
    const float* __restrict__ X, const float* __restrict__ Wp,
    const float* __restrict__ Bp, float* __restrict__ Out)
{
  const int wv = threadIdx.x >> 6, lane = threadIdx.x & 63;
  const size_t row = (size_t)blockIdx.x * 4 + wv;
  const float* xr = X + row * 256;
  float acc = 0.f;
#pragma unroll
  for (int cc = 0; cc < 4; ++cc) acc = fmaf(xr[cc * 64 + lane], Wp[cc * 64 + lane], acc);
#pragma unroll
  for (int off = 1; off < 64; off <<= 1) acc += __shfl_xor(acc, off);
  if (lane == 0) Out[row] = acc + Bp[0];
}

// ============================================================================
extern "C" void kernel_launch(void* const* d_in, const int* in_sizes, int n_in,
                              void* d_out, int out_size, void* d_ws, size_t ws_size,
                              hipStream_t stream)
{
  (void)in_sizes; (void)n_in; (void)out_size; (void)ws_size;
  const float* x      = (const float*)d_in[0];
  const float* y      = (const float*)d_in[1];
  const float* flow   = (const float*)d_in[2];
  const float* w1x1   = (const float*)d_in[3];
  const float* b1x1   = (const float*)d_in[4];
  const float* ca_wq  = (const float*)d_in[5];
  const float* ca_wk  = (const float*)d_in[6];
  const float* ca_wv  = (const float*)d_in[7];
  const float* ca_g   = (const float*)d_in[8];
  const float* cbr1_w = (const float*)d_in[9];
  const float* bn1_g  = (const float*)d_in[10];
  const float* bn1_b  = (const float*)d_in[11];
  const float* sa_wq  = (const float*)d_in[12];
  const float* sa_wk  = (const float*)d_in[13];
  const float* sa_wv  = (const float*)d_in[14];
  const float* sa_g   = (const float*)d_in[15];
  const float* cbr2_w = (const float*)d_in[16];
  const float* bn2_g  = (const float*)d_in[17];
  const float* bn2_b  = (const float*)d_in[18];
  const float* pred_w = (const float*)d_in[19];
  const float* pred_b = (const float*)d_in[20];
  float* out = (float*)d_out;

  // ---- workspace layout (float units)
  const size_t FSZ = (size_t)NB * NPIX * 288;       // 4,718,592 floats
  const size_t SSZ = FSZ / 2;                       // bf16 slot
  float* ws = (float*)d_ws;
  float* F0 = ws;                 // xT -> Opart(1/2) -> conv outs
  float* F1 = ws + FSZ;           // yT -> Opart1 tail -> cat f32
  float* F2 = ws + 2 * FSZ;       // xb f32 (flash1 residual)
  float* Sb = ws + 3 * FSZ;
  __hip_bfloat16* S0 = (__hip_bfloat16*)(Sb);            // xb_bf -> t -> q2
  __hip_bfloat16* S1 = (__hip_bfloat16*)(Sb + SSZ);      // yb_bf -> k2
  __hip_bfloat16* S2 = (__hip_bfloat16*)(Sb + 2 * SSZ);  // q -> v2
  __hip_bfloat16* S3 = (__hip_bfloat16*)(Sb + 3 * SSZ);  // k -> catT
  __hip_bfloat16* S4 = (__hip_bfloat16*)(Sb + 4 * SSZ);  // v -> t2
  float* Wr = Sb + 5 * SSZ;
  __hip_bfloat16* w1bf  = (__hip_bfloat16*)Wr;                       // 256x512
  __hip_bfloat16* caqb  = w1bf + (size_t)256 * 512;                  // 256x256
  __hip_bfloat16* cakb  = caqb + (size_t)256 * 256;
  __hip_bfloat16* cavb  = cakb + (size_t)256 * 256;
  __hip_bfloat16* saqb  = cavb + (size_t)256 * 256;                  // 320x288
  __hip_bfloat16* sakb  = saqb + (size_t)320 * 288;
  __hip_bfloat16* savb  = sakb + (size_t)320 * 288;
  __hip_bfloat16* w2abf = savb + (size_t)320 * 288;                  // 9x256x256
  __hip_bfloat16* w2bbf = w2abf + (size_t)9 * 256 * 256;             // 9x256x288
  float* Part = (float*)(w2bbf + (size_t)9 * 256 * 288);             // 32768
  float* Mean = Part + 32768;                                        // 256
  float* Rstd = Mean + 256;                                          // 256
  float* Mlb  = Rstd + 256;                                          // 131072

  __hip_bfloat16* xT = (__hip_bfloat16*)F0;
  __hip_bfloat16* yT = (__hip_bfloat16*)F1;
  __hip_bfloat16* Op = (__hip_bfloat16*)F0;   // flash partials (F0+F1 for S=4)

  dim3 blk(256);

  // ---- weight prep
  wprep_kernel<<<dim3(256), blk, 0, stream>>>(w1x1, w1bf, 256, 512, 256, 512);
  wprep_kernel<<<dim3(256), blk, 0, stream>>>(ca_wq, caqb, 256, 256, 256, 256);
  wprep_kernel<<<dim3(256), blk, 0, stream>>>(ca_wk, cakb, 256, 256, 256, 256);
  wprep_kernel<<<dim3(256), blk, 0, stream>>>(ca_wv, cavb, 256, 256, 256, 256);
  wprep_kernel<<<dim3(256), blk, 0, stream>>>(sa_wq, saqb, 258, 258, 320, 288);
  wprep_kernel<<<dim3(256), blk, 0, stream>>>(sa_wk, sakb, 258, 258, 320, 288);
  wprep_kernel<<<dim3(256), blk, 0, stream>>>(sa_wv, savb, 258, 258, 320, 288);
  wtransbf_kernel<<<dim3(512), blk, 0, stream>>>(cbr1_w, w2abf, 256, 256, 256);
  wtransbf_kernel<<<dim3(512), blk, 0, stream>>>(cbr2_w, w2bbf, 256, 258, 288);

  // ---- transpose inputs to channel-last bf16
  transp_kernel<<<dim3(8, 64, 4), blk, 0, stream>>>(x, xT);
  transp_kernel<<<dim3(8, 64, 4), blk, 0, stream>>>(y, yT);

  // ---- xb (f32 + bf16), yb (bf16)
  gemm3_kernel<0><<<dim3(64, 4, 4), blk, 0, stream>>>(xT, w1bf, b1x1, F2, S0, 512, 256);
  gemm3_kernel<1><<<dim3(64, 4, 4), blk, 0, stream>>>(yT, w1bf, b1x1, nullptr, S1, 512, 256);

  // ---- cross q [n][C], k chunk, v chunk
  gemm3_kernel<1><<<dim3(64, 4, 4), blk, 0, stream>>>(S0, caqb, nullptr, nullptr, S2, 256, 256);
  gemm3_kernel<3><<<dim3(64, 4, 4), blk, 0, stream>>>(S1, cakb, nullptr, nullptr, S3, 256, 256);
  gemm3_kernel<4><<<dim3(64, 4, 4), blk, 0, stream>>>(S1, cavb, nullptr, nullptr, S4, 256, 256);

  // ---- cross flash (QB=32, split 4) + merge: t = gamma*attn + xb -> S0
  flash4_kernel<256, 2, 4><<<dim3(32, 4, 4), blk, 0, stream>>>(S2, S3, S4, Op, Mlb);
  merge4_kernel<256, 4><<<dim3(16384), blk, 0, stream>>>(Op, Mlb, F2, ca_g, S0);

  // ---- conv1 + BN + ReLU + cat
  conv3_kernel<256><<<dim3(64, 4, 4), blk, 0, stream>>>(S0, w2abf, F0);
  stats1_kernel<<<dim3(256), blk, 0, stream>>>(F0, Part);
  stats2_kernel<<<dim3(1), blk, 0, stream>>>(Part, Mean, Rstd);
  bnapply1_kernel<<<dim3(16384), dim3(320), 0, stream>>>(F0, flow, Mean, Rstd,
                                                         bn1_g, bn1_b, F1, S3);

  // ---- self q2 [n][288], k2 chunk, v2 chunk
  gemm3_kernel<1><<<dim3(64, 5, 4), blk, 0, stream>>>(S3, saqb, nullptr, nullptr, S0, 288, 288);
  gemm3_kernel<3><<<dim3(64, 5, 4), blk, 0, stream>>>(S3, sakb, nullptr, nullptr, S1, 288, 288);
  gemm3_kernel<4><<<dim3(64, 5, 4), blk, 0, stream>>>(S3, savb, nullptr, nullptr, S2, 288, 288);

  // ---- self flash (QB=16, split 2) + merge: t2 -> S4
  flash4_kernel<288, 1, 2><<<dim3(64, 2, 4), blk, 0, stream>>>(S0, S1, S2, Op, Mlb);
  merge4_kernel<288, 2><<<dim3(16384), blk, 0, stream>>>(Op, Mlb, F1, sa_g, S4);

  // ---- conv2 + BN + ReLU (in place), pred
  conv3_kernel<288><<<dim3(64, 4, 4), blk, 0, stream>>>(S4, w2bbf, F0);
  stats1_kernel<<<dim3(256), blk, 0, stream>>>(F0, Part);
  stats2_kernel<<<dim3(1), blk, 0, stream>>>(Part, Mean, Rstd);
  bnapply2_kernel<<<dim3(16384), blk, 0, stream>>>(F0, Mean, Rstd, bn2_g, bn2_b);

  pred3_kernel<<<dim3(4096), blk, 0, stream>>>(F0, pred_w, pred_b, out);
}